// Round 8
// baseline (391.684 us; speedup 1.0000x reference)
//
#include <hip/hip_runtime.h>
#include <math.h>

#define DIMC   1024
#define NTOK   2048
#define BATCH  2
#define HEADS  16
#define HDIM   64
#define HIDDEN 4096
#define MROWS  (BATCH*NTOK)                      /* 4096 token-rows */
#define QSZ    ((size_t)BATCH*HEADS*NTOK*HDIM)   /* 4194304 */
#define QSC    0.18033688f                       /* 64^-0.5 * log2(e), folded into q */

typedef unsigned short ushort_t;
typedef __attribute__((ext_vector_type(8))) short short8;
typedef __attribute__((ext_vector_type(4))) float f32x4;
typedef __attribute__((ext_vector_type(4))) unsigned short us4;

__device__ __forceinline__ ushort_t f2b(float f) {
  union { float f; unsigned int u; } cv; cv.f = f;
  unsigned int u = cv.u;
  unsigned int r = (u + 0x7fffu + ((u >> 16) & 1u)) >> 16;  // RNE
  return (ushort_t)r;
}

__device__ __forceinline__ float b2f(ushort_t b) {
  union { unsigned int u; float f; } cv; cv.u = ((unsigned int)b) << 16;
  return cv.f;
}

__device__ __forceinline__ float fexp2(float x) {
#if __has_builtin(__builtin_amdgcn_exp2f)
  return __builtin_amdgcn_exp2f(x);
#else
  return exp2f(x);
#endif
}

__device__ __forceinline__ void gl_lds16(const void* g, void* l) {
  __builtin_amdgcn_global_load_lds(
      (const __attribute__((address_space(1))) void*)g,
      (__attribute__((address_space(3))) void*)l, 16, 0, 0);
}

// ---- fused pre-pass: transpose x (B,C,N)->xt (B,N,C) bf16  +  w fp32->bf16 --
// blocks [0,4096): transpose tiles; [4096,16384): weight convert (one launch
// instead of two -> one fewer inter-kernel gap).
__global__ __launch_bounds__(256) void k_pre(const float* __restrict__ x,
                                             const float* __restrict__ w0,
                                             const float* __restrict__ w1,
                                             const float* __restrict__ w2,
                                             const float* __restrict__ w3,
                                             ushort_t* __restrict__ xt,
                                             ushort_t* __restrict__ o0,
                                             ushort_t* __restrict__ o1,
                                             ushort_t* __restrict__ o2,
                                             ushort_t* __restrict__ o3) {
  __shared__ float t[32][33];
  int bid = blockIdx.x;
  if (bid < 4096) {  // transpose path
    int b   = bid >> 11;          // 2048 tiles per batch
    int rem = bid & 2047;
    int n0  = (rem & 63) * 32;    // 64 n-tiles
    int c0  = (rem >> 6) * 32;    // 32 c-tiles
    int tx = threadIdx.x & 31, ty = threadIdx.x >> 5;  // (32,8)
#pragma unroll
    for (int l = 0; l < 4; l++)
      t[ty + l * 8][tx] = x[((size_t)(b * DIMC + c0 + ty + l * 8)) * NTOK + n0 + tx];
    __syncthreads();
#pragma unroll
    for (int l = 0; l < 4; l++)
      xt[((size_t)(b * NTOK + n0 + ty + l * 8)) * DIMC + c0 + tx] = f2b(t[tx][ty + l * 8]);
  } else {  // weight-convert path
    int cb = bid - 4096;
    const float* in; ushort_t* out; int base;
    if (cb < 3072)      { in = w0; out = o0; base = cb; }
    else if (cb < 4096) { in = w1; out = o1; base = cb - 3072; }
    else if (cb < 8192) { in = w2; out = o2; base = cb - 4096; }
    else                { in = w3; out = o3; base = cb - 8192; }
    int i = base * 256 + threadIdx.x;
    float4 v = ((const float4*)in)[i];
    us4 o; o.x = f2b(v.x); o.y = f2b(v.y); o.z = f2b(v.z); o.w = f2b(v.w);
    ((us4*)out)[i] = o;
  }
}

// ---------------- bf16 MFMA GEMM: out = A(MxK) @ W(NcolsxK)^T + bias ---------
// 128x128 tile, 4 waves x 64x64, 16x16x32 MFMA. Direct global_load_lds
// staging (m97 structure): LDS is lane-linear, swizzle pre-applied on the
// GLOBAL source chunk (gch), fragment reads undo it (sw8). Double-buffered,
// one __syncthreads per 32-K step (drains vmcnt -> staged tile visible).
// XCD-aware 1D grid on blockIdx.x. Split-K via blockIdx.y (kz).
// EPI: 0 = qkv -> bf16 q(*QSC)/k/vT scatter, 2 = fc1 raw bf16 (GELU in LN),
//      4 = raw bf16 partial (no bias) at outv + kz*MROWS*DIMC
template <int EPI, int NTX8, int KSTRIDE, int KLEN>
__global__ __launch_bounds__(256) void k_gemm_bf16(const ushort_t* __restrict__ A,
                                                   const ushort_t* __restrict__ W,
                                                   const float* __restrict__ bias,
                                                   void* __restrict__ outv) {
  __shared__ ushort_t As[2][128 * 32];
  __shared__ ushort_t Bs[2][128 * 32];
  const int tid = threadIdx.x;
  const int lane = tid & 63, wv = tid >> 6;
  const int bid = blockIdx.x, kz = blockIdx.y;
  const int xcd = bid & 7, t = bid >> 3;
  const int row0 = (t / NTX8) * 128;
  const int col0 = (xcd * NTX8 + (t % NTX8)) * 128;
  const int wrow0 = (wv >> 1) * 64, wcol0 = (wv & 1) * 64;
  const int lm = lane & 15, lq = lane >> 4;
  const int srow = wv * 32 + (lane >> 2);              // global row this lane stages
  const int gch = (lane & 3) ^ ((lane >> 3) & 3);      // swizzled global chunk
  const int sw8 = (lq ^ ((lm >> 1) & 3)) * 8;          // fragment read slot

  const ushort_t* Ab = A + (size_t)(row0 + srow) * KSTRIDE + (size_t)kz * KLEN + gch * 8;
  const ushort_t* Wb = W + (size_t)(col0 + srow) * KSTRIDE + (size_t)kz * KLEN + gch * 8;
  const size_t rstep = (size_t)16 * KSTRIDE;

  f32x4 acc[4][4];
#pragma unroll
  for (int i = 0; i < 4; i++)
#pragma unroll
    for (int j = 0; j < 4; j++) acc[i][j] = (f32x4){0.f, 0.f, 0.f, 0.f};

  // dest: wave-uniform base; HW scatters lane*16B -> byte wv*2048 + lane*16,
  // which is exactly row srow (=wv*32+lane>>2), slot (lane&3) of the old layout.
#define STAGE(buf, k0) do {                                      \
    gl_lds16(Ab + (k0),         &As[buf][wv * 1024]);            \
    gl_lds16(Ab + rstep + (k0), &As[buf][wv * 1024 + 512]);      \
    gl_lds16(Wb + (k0),         &Bs[buf][wv * 1024]);            \
    gl_lds16(Wb + rstep + (k0), &Bs[buf][wv * 1024 + 512]);      \
  } while (0)

  auto compute = [&](int buf) {
    short8 af[4], bf[4];
#pragma unroll
    for (int mi = 0; mi < 4; mi++)
      af[mi] = *(const short8*)&As[buf][(wrow0 + mi * 16 + lm) * 32 + sw8];
#pragma unroll
    for (int ni = 0; ni < 4; ni++)
      bf[ni] = *(const short8*)&Bs[buf][(wcol0 + ni * 16 + lm) * 32 + sw8];
#pragma unroll
    for (int mi = 0; mi < 4; mi++)
#pragma unroll
      for (int ni = 0; ni < 4; ni++)
        acc[mi][ni] = __builtin_amdgcn_mfma_f32_16x16x32_bf16(af[mi], bf[ni], acc[mi][ni], 0, 0, 0);
  };

  constexpr int S = KLEN / 32;
  STAGE(0, 0);                                   // prologue: tile 0 -> buf 0
#pragma unroll 1
  for (int kk = 0; kk < S; kk++) {
    __syncthreads();                             // drains vmcnt: tile kk resident;
                                                 // prev compute's ds_reads done
    if (kk + 1 < S) STAGE((kk + 1) & 1, (kk + 1) * 32);  // prefetch overlaps MFMA
    compute(kk & 1);
  }
#undef STAGE

#pragma unroll
  for (int mi = 0; mi < 4; mi++) {
#pragma unroll
    for (int ni = 0; ni < 4; ni++) {
#pragma unroll
      for (int r = 0; r < 4; r++) {
        const int row = row0 + wrow0 + mi * 16 + lq * 4 + r;
        const int col = col0 + wcol0 + ni * 16 + lm;
        float v = acc[mi][ni][r];
        if (EPI != 4) v += bias[col];
        if (EPI == 0) {  // qkv scatter: col = which*1024 + h*64 + d; bf16 outputs
          int which = col >> 10, rem = col & 1023, hh = rem >> 6, d = rem & 63;
          int bb = row >> 11, n = row & 2047;
          size_t bh = (size_t)(bb * HEADS + hh);
          ushort_t* o16 = (ushort_t*)outv;
          if (which == 0)
            o16[(bh * NTOK + n) * HDIM + d] = f2b(v * QSC);  // fold scale*log2e
          else if (which == 1)
            o16[QSZ + (bh * NTOK + n) * HDIM + d] = f2b(v);
          else
            o16[2 * QSZ + (bh * HDIM + d) * NTOK + n] = f2b(v);
        } else if (EPI == 2) {  // fc1 raw (GELU applied in LN kernel)
          ((ushort_t*)outv)[(size_t)row * HIDDEN + col] = f2b(v);
        } else {  // EPI==4: raw bf16 partial for split-K
          ((ushort_t*)outv)[(size_t)kz * MROWS * DIMC + (size_t)row * DIMC + col] = f2b(v);
        }
      }
    }
  }
}

// ------- combine proj partials (4-way split-K): hb = bf16(2*(sum+bias)) ------
__global__ __launch_bounds__(256) void k_comb_proj(const ushort_t* __restrict__ p,
                                                   const float* __restrict__ bias,
                                                   ushort_t* __restrict__ hb) {
  const size_t SL = (size_t)MROWS * DIMC / 4;      // us4 elems per slice
  size_t i = (size_t)blockIdx.x * 256 + threadIdx.x;
  int colb = ((int)i & 255) * 4;
  us4 a0 = ((const us4*)p)[i];
  us4 a1 = ((const us4*)p)[i + SL];
  us4 a2 = ((const us4*)p)[i + 2 * SL];
  us4 a3 = ((const us4*)p)[i + 3 * SL];
  us4 o;
  o.x = f2b(2.f * (b2f(a0.x) + b2f(a1.x) + b2f(a2.x) + b2f(a3.x) + bias[colb + 0]));
  o.y = f2b(2.f * (b2f(a0.y) + b2f(a1.y) + b2f(a2.y) + b2f(a3.y) + bias[colb + 1]));
  o.z = f2b(2.f * (b2f(a0.z) + b2f(a1.z) + b2f(a2.z) + b2f(a3.z) + bias[colb + 2]));
  o.w = f2b(2.f * (b2f(a0.w) + b2f(a1.w) + b2f(a2.w) + b2f(a3.w) + bias[colb + 3]));
  ((us4*)hb)[i] = o;
}

// --- combine fc2 partials (4-way) + residual, transposed store to (B,C,N) ----
__global__ __launch_bounds__(256) void k_comb_fc2(const ushort_t* __restrict__ p,
                                                  const ushort_t* __restrict__ hb,
                                                  const float* __restrict__ bias,
                                                  float* __restrict__ out) {
  __shared__ float t[32][33];
  const size_t SL = (size_t)MROWS * DIMC;
  int b  = blockIdx.z;
  int c0 = blockIdx.y * 32, n0 = blockIdx.x * 32;
  int tx = threadIdx.x, ty = threadIdx.y;  // (32,8)
#pragma unroll
  for (int l = 0; l < 4; l++) {
    size_t idx = ((size_t)(b * NTOK + n0 + ty + l * 8)) * DIMC + c0 + tx;
    t[ty + l * 8][tx] = b2f(p[idx]) + b2f(p[idx + SL]) + b2f(p[idx + 2 * SL]) +
                        b2f(p[idx + 3 * SL]) + b2f(hb[idx]) + bias[c0 + tx];
  }
  __syncthreads();
#pragma unroll
  for (int l = 0; l < 4; l++)
    out[((size_t)(b * DIMC + c0 + ty + l * 8)) * NTOK + n0 + tx] = t[tx][ty + l * 8];
}

// ---------------- MFMA flash attention, fixed-max softmax_one ----------------
// out' = e^x/(1+Sum e^x) (max-sub dropped: ~2e-4 abs err; masked rows p=1
// exactly). Row-sum via ones-MFMA. q pre-scaled by SCALE*log2e. K/V double-
// buffered, one barrier per tile. (Round-0 structure — best measured 65.2us;
// setprio regressed, QBLK=64 regressed, 32x32 swapped-QK was parity, direct-
// L2 K/V regressed 2x. Staged-LDS 16x16 is the verified local optimum.)
__global__ __launch_bounds__(256) void k_attn_mfma(const ushort_t* __restrict__ qkv,
                                                   const int* __restrict__ mask,
                                                   ushort_t* __restrict__ scram) {
  __shared__ ushort_t Kl[2][64 * 64];
  __shared__ ushort_t Vl[2][64 * 64];
  __shared__ ushort_t Pl[4 * 32 * 72];
  const int tid = threadIdx.x;
  const int lane = tid & 63, w = tid >> 6;
  const int lm = lane & 15, quad = lane >> 4;
  const int bh = blockIdx.y, b = bh >> 4, h = bh & 15;
  const int q0 = blockIdx.x * 128 + w * 32;
  const ushort_t* qg  = qkv + (size_t)bh * NTOK * HDIM;
  const ushort_t* kg  = qkv + QSZ + (size_t)bh * NTOK * HDIM;
  const ushort_t* vTg = qkv + 2 * QSZ + (size_t)bh * HDIM * NTOK;
  ushort_t* Pw = &Pl[w * 32 * 72];

  const short8 ones = {0x3F80, 0x3F80, 0x3F80, 0x3F80, 0x3F80, 0x3F80, 0x3F80, 0x3F80};

  // Q fragments (A-layout): m=lm, k=hf*32+quad*8+j  — register-resident
  short8 qf[2][2];
#pragma unroll
  for (int qs = 0; qs < 2; qs++)
#pragma unroll
    for (int hf = 0; hf < 2; hf++)
      qf[qs][hf] = *(const short8*)&qg[(size_t)(q0 + qs * 16 + lm) * HDIM + hf * 32 + quad * 8];

  bool mk[2][4];
#pragma unroll
  for (int qs = 0; qs < 2; qs++)
#pragma unroll
    for (int r = 0; r < 4; r++)
      mk[qs][r] = mask[(size_t)bh * NTOK + q0 + qs * 16 + quad * 4 + r] != 0;

  f32x4 O[2][4], La[2];
#pragma unroll
  for (int qs = 0; qs < 2; qs++) {
    La[qs] = (f32x4){0.f, 0.f, 0.f, 0.f};
#pragma unroll
    for (int r = 0; r < 4; r++) O[qs][r] = (f32x4){0.f, 0.f, 0.f, 0.f};
  }

  // staging indices: slot s (16B) -> row s>>3, stores global chunk (s&7)^(row&7)
  const int s0 = tid, s1 = tid + 256;
  const int r0 = s0 >> 3, g0 = (s0 & 7) ^ (r0 & 7);
  const int r1 = s1 >> 3, g1 = (s1 & 7) ^ (r1 & 7);

  // preload tile 0 into buffer 0
  gl_lds16(kg + (size_t)r0 * HDIM + g0 * 8, &Kl[0][s0 * 8]);
  gl_lds16(kg + (size_t)r1 * HDIM + g1 * 8, &Kl[0][s1 * 8]);
  gl_lds16(vTg + (size_t)r0 * NTOK + g0 * 8, &Vl[0][s0 * 8]);
  gl_lds16(vTg + (size_t)r1 * NTOK + g1 * 8, &Vl[0][s1 * 8]);

  for (int kt = 0; kt < NTOK; kt += 64) {
    const int cur = (kt >> 6) & 1, nxt = cur ^ 1;
    __syncthreads();  // drains vmcnt: tile kt resident; prior tile's reads done
    if (kt + 64 < NTOK) {  // async-stage next tile; lands before next barrier
      gl_lds16(kg + (size_t)(kt + 64 + r0) * HDIM + g0 * 8, &Kl[nxt][s0 * 8]);
      gl_lds16(kg + (size_t)(kt + 64 + r1) * HDIM + g1 * 8, &Kl[nxt][s1 * 8]);
      gl_lds16(vTg + (size_t)r0 * NTOK + kt + 64 + g0 * 8, &Vl[nxt][s0 * 8]);
      gl_lds16(vTg + (size_t)r1 * NTOK + kt + 64 + g1 * 8, &Vl[nxt][s1 * 8]);
    }

    // K fragments (B-layout): n=key=ksub*16+lm, k=hf*32+quad*8+j
    short8 kf[4][2];
#pragma unroll
    for (int ksub = 0; ksub < 4; ksub++)
#pragma unroll
      for (int hf = 0; hf < 2; hf++)
        kf[ksub][hf] = *(const short8*)&Kl[cur][(ksub * 16 + lm) * 64 + ((4 * hf + quad) ^ (lm & 7)) * 8];

#pragma unroll
    for (int qs = 0; qs < 2; qs++) {
      f32x4 S[4];
#pragma unroll
      for (int ksub = 0; ksub < 4; ksub++) {
        S[ksub] = (f32x4){0.f, 0.f, 0.f, 0.f};
        S[ksub] = __builtin_amdgcn_mfma_f32_16x16x32_bf16(qf[qs][0], kf[ksub][0], S[ksub], 0, 0, 0);
        S[ksub] = __builtin_amdgcn_mfma_f32_16x16x32_bf16(qf[qs][1], kf[ksub][1], S[ksub], 0, 0, 0);
      }
      // p = exp2(s) (q pre-scaled); masked rows: p = 1 exactly. Truncation cvt.
#pragma unroll
      for (int r = 0; r < 4; r++) {
        const int prow = qs * 16 + quad * 4 + r;
#pragma unroll
        for (int ksub = 0; ksub < 4; ksub++) {
          float p = mk[qs][r] ? fexp2(S[ksub][r]) : 1.0f;
          Pw[prow * 72 + ksub * 16 + lm] = (ushort_t)(__float_as_uint(p) >> 16);
        }
      }
    }
    __builtin_amdgcn_s_waitcnt(0xC07F);  // drain P ds_writes (same-wave RAW)

    // V fragments (B-layout): n=d=dsub*16+lm, k=key=hf*32+quad*8+j from vT LDS
    short8 vf[4][2];
#pragma unroll
    for (int dsub = 0; dsub < 4; dsub++)
#pragma unroll
      for (int hf = 0; hf < 2; hf++)
        vf[dsub][hf] = *(const short8*)&Vl[cur][(dsub * 16 + lm) * 64 + ((4 * hf + quad) ^ (lm & 7)) * 8];

#pragma unroll
    for (int qs = 0; qs < 2; qs++) {
      short8 pf[2];
#pragma unroll
      for (int hf = 0; hf < 2; hf++)
        pf[hf] = *(const short8*)&Pw[(qs * 16 + lm) * 72 + hf * 32 + quad * 8];
#pragma unroll
      for (int dsub = 0; dsub < 4; dsub++) {
        O[qs][dsub] = __builtin_amdgcn_mfma_f32_16x16x32_bf16(pf[0], vf[dsub][0], O[qs][dsub], 0, 0, 0);
        O[qs][dsub] = __builtin_amdgcn_mfma_f32_16x16x32_bf16(pf[1], vf[dsub][1], O[qs][dsub], 0, 0, 0);
      }
      La[qs] = __builtin_amdgcn_mfma_f32_16x16x32_bf16(pf[0], ones, La[qs], 0, 0, 0);
      La[qs] = __builtin_amdgcn_mfma_f32_16x16x32_bf16(pf[1], ones, La[qs], 0, 0, 0);
    }
  }

  // epilogue: /(1+l), scrambled merge (b,h,n,d) -> row d*32+h*2+(n>>10), col n&1023
#pragma unroll
  for (int qs = 0; qs < 2; qs++)
#pragma unroll
    for (int r = 0; r < 4; r++) {
      int n = q0 + qs * 16 + quad * 4 + r;
      float inv = 1.f / (1.f + La[qs][r]);
      int n1 = n >> 10, nn0 = n & 1023;
#pragma unroll
      for (int dsub = 0; dsub < 4; dsub++) {
        int d = dsub * 16 + lm;
        int np = d * 32 + h * 2 + n1;
        scram[((size_t)(b * NTOK + np)) * DIMC + nn0] = f2b(O[qs][dsub][r] * inv);
      }
    }
}

// ---------------- GELU (exact, erf) + row LayerNorm over HIDDEN=4096 ---------
__global__ __launch_bounds__(256) void k_ln(ushort_t* __restrict__ mid,
                                            const float* __restrict__ g,
                                            const float* __restrict__ bta) {
  const int row = blockIdx.x;
  ushort_t* p = mid + (size_t)row * HIDDEN;
  const int tid = threadIdx.x;
  float lv[16];
  float s = 0.f, s2 = 0.f;
#pragma unroll
  for (int i = 0; i < 4; i++) {
    us4 u = *(const us4*)&p[tid * 4 + i * 1024];
#pragma unroll
    for (int j = 0; j < 4; j++) {
      float xx = b2f((j == 0) ? u.x : (j == 1) ? u.y : (j == 2) ? u.z : u.w);
      xx = 0.5f * xx * (1.f + erff(xx * 0.70710678118654752f));  // exact GELU
      lv[i * 4 + j] = xx;
      s += xx;
      s2 += xx * xx;
    }
  }
#pragma unroll
  for (int off = 32; off > 0; off >>= 1) {
    s += __shfl_down(s, off);
    s2 += __shfl_down(s2, off);
  }
  __shared__ float rs[4], rs2[4];
  if ((tid & 63) == 0) { rs[tid >> 6] = s; rs2[tid >> 6] = s2; }
  __syncthreads();
  float ts = rs[0] + rs[1] + rs[2] + rs[3];
  float ts2 = rs2[0] + rs2[1] + rs2[2] + rs2[3];
  float mu = ts * (1.f / HIDDEN);
  float var = ts2 * (1.f / HIDDEN) - mu * mu;
  float rstd = rsqrtf(var + 1e-5f);
#pragma unroll
  for (int i = 0; i < 4; i++) {
    us4 o;
#pragma unroll
    for (int j = 0; j < 4; j++) {
      int f = tid * 4 + i * 1024 + j;
      float y = (lv[i * 4 + j] - mu) * rstd * g[f] + bta[f];
      ushort_t ob = f2b(y);
      if (j == 0) o.x = ob; else if (j == 1) o.y = ob; else if (j == 2) o.z = ob; else o.w = ob;
    }
    *(us4*)&p[tid * 4 + i * 1024] = o;
  }
}

extern "C" void kernel_launch(void* const* d_in, const int* in_sizes, int n_in,
                              void* d_out, int out_size, void* d_ws, size_t ws_size,
                              hipStream_t stream) {
  const float* x      = (const float*)d_in[0];
  const int*   mask   = (const int*)d_in[1];
  const float* qkv_w  = (const float*)d_in[2];
  const float* qkv_b  = (const float*)d_in[3];
  const float* proj_w = (const float*)d_in[4];
  const float* proj_b = (const float*)d_in[5];
  const float* fc1_w  = (const float*)d_in[6];
  const float* fc1_b  = (const float*)d_in[7];
  const float* ln_g   = (const float*)d_in[8];
  const float* ln_b   = (const float*)d_in[9];
  const float* fc2_w  = (const float*)d_in[10];
  const float* fc2_b  = (const float*)d_in[11];

  char* w = (char*)d_ws;
  ushort_t* qkv16  = (ushort_t*)w;           w += 3 * QSZ * 2;                    // 25.2 MB
  ushort_t* xtb    = (ushort_t*)w;           w += (size_t)MROWS * DIMC * 2;       //  8.4 MB
  ushort_t* scramb = (ushort_t*)w;           w += (size_t)MROWS * DIMC * 2;       //  8.4 MB
  ushort_t* hb     = (ushort_t*)w;           w += (size_t)MROWS * DIMC * 2;       //  8.4 MB
  ushort_t* mid    = (ushort_t*)w;           w += (size_t)MROWS * HIDDEN * 2;     // 33.6 MB
  ushort_t* wqkvb  = (ushort_t*)w;           w += (size_t)3 * DIMC * DIMC * 2;    //  6.3 MB
  ushort_t* wprojb = (ushort_t*)w;           w += (size_t)DIMC * DIMC * 2;        //  2.1 MB
  ushort_t* wfc1b  = (ushort_t*)w;           w += (size_t)HIDDEN * DIMC * 2;      //  8.4 MB
  ushort_t* wfc2b  = (ushort_t*)w;           w += (size_t)DIMC * HIDDEN * 2;      //  8.4 MB
  ushort_t* pbuf   = (ushort_t*)w;           w += (size_t)4 * MROWS * DIMC * 2;   // 33.6 MB (4x bf16 partials)

  k_pre<<<dim3(4096 + 12288), 256, 0, stream>>>(x, qkv_w, proj_w, fc1_w, fc2_w,
                                                xtb, wqkvb, wprojb, wfc1b, wfc2b);

  // 1D grids: (ntx*nty) with ntx = cols/128 (divisible by 8), nty = rows/128
  k_gemm_bf16<0, 3, DIMC, DIMC><<<dim3(24 * 32), 256, 0, stream>>>(
      xtb, wqkvb, qkv_b, qkv16);
  k_attn_mfma<<<dim3(NTOK / 128, BATCH * HEADS), 256, 0, stream>>>(
      qkv16, mask, scramb);
  // proj: split-K=4 (K=1024 -> 4x256), bf16 partials -> 1024 WGs (~4 blk/CU)
  k_gemm_bf16<4, 1, DIMC, 256><<<dim3(8 * 32, 4), 256, 0, stream>>>(
      scramb, wprojb, nullptr, pbuf);
  k_comb_proj<<<dim3(4096), 256, 0, stream>>>(pbuf, proj_b, hb);
  k_gemm_bf16<2, 4, DIMC, DIMC><<<dim3(32 * 32), 256, 0, stream>>>(
      hb, wfc1b, fc1_b, mid);
  k_ln<<<dim3(MROWS), 256, 0, stream>>>(mid, ln_g, ln_b);
  // fc2: split-K=4 (K=4096 -> 4x1024) -> 1024 WGs (~4 blk/CU)
  k_gemm_bf16<4, 1, HIDDEN, 1024><<<dim3(8 * 32, 4), 256, 0, stream>>>(
      mid, wfc2b, nullptr, pbuf);
  k_comb_fc2<<<dim3(NTOK / 32, DIMC / 32, BATCH), dim3(32, 8), 0, stream>>>(
      pbuf, hb, fc2_b, (float*)d_out);
}

// Round 9
// 376.546 us; speedup vs baseline: 1.0402x; 1.0402x over previous
//
#include <hip/hip_runtime.h>
#include <math.h>

#define DIMC   1024
#define NTOK   2048
#define BATCH  2
#define HEADS  16
#define HDIM   64
#define HIDDEN 4096
#define MROWS  (BATCH*NTOK)                      /* 4096 token-rows */
#define QSZ    ((size_t)BATCH*HEADS*NTOK*HDIM)   /* 4194304 */
#define QSC    0.18033688f                       /* 64^-0.5 * log2(e), folded into q */

typedef unsigned short ushort_t;
typedef __attribute__((ext_vector_type(8))) short short8;
typedef __attribute__((ext_vector_type(4))) float f32x4;
typedef __attribute__((ext_vector_type(4))) unsigned short us4;

__device__ __forceinline__ ushort_t f2b(float f) {
  union { float f; unsigned int u; } cv; cv.f = f;
  unsigned int u = cv.u;
  unsigned int r = (u + 0x7fffu + ((u >> 16) & 1u)) >> 16;  // RNE
  return (ushort_t)r;
}

__device__ __forceinline__ float b2f(ushort_t b) {
  union { unsigned int u; float f; } cv; cv.u = ((unsigned int)b) << 16;
  return cv.f;
}

__device__ __forceinline__ float fexp2(float x) {
#if __has_builtin(__builtin_amdgcn_exp2f)
  return __builtin_amdgcn_exp2f(x);
#else
  return exp2f(x);
#endif
}

__device__ __forceinline__ void gl_lds16(const void* g, void* l) {
  __builtin_amdgcn_global_load_lds(
      (const __attribute__((address_space(1))) void*)g,
      (__attribute__((address_space(3))) void*)l, 16, 0, 0);
}

// ---- fused pre-pass: transpose x (B,C,N)->xt (B,N,C) bf16  +  w fp32->bf16 --
// blocks [0,4096): transpose tiles; [4096,16384): weight convert (one launch
// instead of two -> one fewer inter-kernel gap).
__global__ __launch_bounds__(256) void k_pre(const float* __restrict__ x,
                                             const float* __restrict__ w0,
                                             const float* __restrict__ w1,
                                             const float* __restrict__ w2,
                                             const float* __restrict__ w3,
                                             ushort_t* __restrict__ xt,
                                             ushort_t* __restrict__ o0,
                                             ushort_t* __restrict__ o1,
                                             ushort_t* __restrict__ o2,
                                             ushort_t* __restrict__ o3) {
  __shared__ float t[32][33];
  int bid = blockIdx.x;
  if (bid < 4096) {  // transpose path
    int b   = bid >> 11;          // 2048 tiles per batch
    int rem = bid & 2047;
    int n0  = (rem & 63) * 32;    // 64 n-tiles
    int c0  = (rem >> 6) * 32;    // 32 c-tiles
    int tx = threadIdx.x & 31, ty = threadIdx.x >> 5;  // (32,8)
#pragma unroll
    for (int l = 0; l < 4; l++)
      t[ty + l * 8][tx] = x[((size_t)(b * DIMC + c0 + ty + l * 8)) * NTOK + n0 + tx];
    __syncthreads();
#pragma unroll
    for (int l = 0; l < 4; l++)
      xt[((size_t)(b * NTOK + n0 + ty + l * 8)) * DIMC + c0 + tx] = f2b(t[tx][ty + l * 8]);
  } else {  // weight-convert path
    int cb = bid - 4096;
    const float* in; ushort_t* out; int base;
    if (cb < 3072)      { in = w0; out = o0; base = cb; }
    else if (cb < 4096) { in = w1; out = o1; base = cb - 3072; }
    else if (cb < 8192) { in = w2; out = o2; base = cb - 4096; }
    else                { in = w3; out = o3; base = cb - 8192; }
    int i = base * 256 + threadIdx.x;
    float4 v = ((const float4*)in)[i];
    us4 o; o.x = f2b(v.x); o.y = f2b(v.y); o.z = f2b(v.z); o.w = f2b(v.w);
    ((us4*)out)[i] = o;
  }
}

// ---------------- bf16 MFMA GEMM: out = A(MxK) @ W(NcolsxK)^T + bias ---------
// 128x128 tile, 4 waves x 64x64, 16x16x32 MFMA. Direct global_load_lds
// staging (m97 structure): LDS is lane-linear, swizzle pre-applied on the
// GLOBAL source chunk (gch), fragment reads undo it (sw8). Double-buffered,
// one __syncthreads per 32-K step (drains vmcnt -> staged tile visible).
// XCD-aware 1D grid on blockIdx.x. Split-K via blockIdx.y (kz) — 2-way only:
// 4-way measured -7us (doubles partial round-trip, halves K-loop amortization).
// EPI: 0 = qkv -> bf16 q(*QSC)/k/vT scatter, 2 = fc1 raw bf16 (GELU in LN),
//      4 = raw bf16 partial (no bias) at outv + kz*MROWS*DIMC
template <int EPI, int NTX8, int KSTRIDE, int KLEN>
__global__ __launch_bounds__(256) void k_gemm_bf16(const ushort_t* __restrict__ A,
                                                   const ushort_t* __restrict__ W,
                                                   const float* __restrict__ bias,
                                                   void* __restrict__ outv) {
  __shared__ ushort_t As[2][128 * 32];
  __shared__ ushort_t Bs[2][128 * 32];
  const int tid = threadIdx.x;
  const int lane = tid & 63, wv = tid >> 6;
  const int bid = blockIdx.x, kz = blockIdx.y;
  const int xcd = bid & 7, t = bid >> 3;
  const int row0 = (t / NTX8) * 128;
  const int col0 = (xcd * NTX8 + (t % NTX8)) * 128;
  const int wrow0 = (wv >> 1) * 64, wcol0 = (wv & 1) * 64;
  const int lm = lane & 15, lq = lane >> 4;
  const int srow = wv * 32 + (lane >> 2);              // global row this lane stages
  const int gch = (lane & 3) ^ ((lane >> 3) & 3);      // swizzled global chunk
  const int sw8 = (lq ^ ((lm >> 1) & 3)) * 8;          // fragment read slot

  const ushort_t* Ab = A + (size_t)(row0 + srow) * KSTRIDE + (size_t)kz * KLEN + gch * 8;
  const ushort_t* Wb = W + (size_t)(col0 + srow) * KSTRIDE + (size_t)kz * KLEN + gch * 8;
  const size_t rstep = (size_t)16 * KSTRIDE;

  f32x4 acc[4][4];
#pragma unroll
  for (int i = 0; i < 4; i++)
#pragma unroll
    for (int j = 0; j < 4; j++) acc[i][j] = (f32x4){0.f, 0.f, 0.f, 0.f};

  // dest: wave-uniform base; HW scatters lane*16B -> byte wv*2048 + lane*16,
  // which is exactly row srow (=wv*32+lane>>2), slot (lane&3) of the old layout.
#define STAGE(buf, k0) do {                                      \
    gl_lds16(Ab + (k0),         &As[buf][wv * 1024]);            \
    gl_lds16(Ab + rstep + (k0), &As[buf][wv * 1024 + 512]);      \
    gl_lds16(Wb + (k0),         &Bs[buf][wv * 1024]);            \
    gl_lds16(Wb + rstep + (k0), &Bs[buf][wv * 1024 + 512]);      \
  } while (0)

  auto compute = [&](int buf) {
    short8 af[4], bf[4];
#pragma unroll
    for (int mi = 0; mi < 4; mi++)
      af[mi] = *(const short8*)&As[buf][(wrow0 + mi * 16 + lm) * 32 + sw8];
#pragma unroll
    for (int ni = 0; ni < 4; ni++)
      bf[ni] = *(const short8*)&Bs[buf][(wcol0 + ni * 16 + lm) * 32 + sw8];
#pragma unroll
    for (int mi = 0; mi < 4; mi++)
#pragma unroll
      for (int ni = 0; ni < 4; ni++)
        acc[mi][ni] = __builtin_amdgcn_mfma_f32_16x16x32_bf16(af[mi], bf[ni], acc[mi][ni], 0, 0, 0);
  };

  constexpr int S = KLEN / 32;
  STAGE(0, 0);                                   // prologue: tile 0 -> buf 0
#pragma unroll 1
  for (int kk = 0; kk < S; kk++) {
    __syncthreads();                             // drains vmcnt: tile kk resident;
                                                 // prev compute's ds_reads done
    if (kk + 1 < S) STAGE((kk + 1) & 1, (kk + 1) * 32);  // prefetch overlaps MFMA
    compute(kk & 1);
  }
#undef STAGE

#pragma unroll
  for (int mi = 0; mi < 4; mi++) {
#pragma unroll
    for (int ni = 0; ni < 4; ni++) {
#pragma unroll
      for (int r = 0; r < 4; r++) {
        const int row = row0 + wrow0 + mi * 16 + lq * 4 + r;
        const int col = col0 + wcol0 + ni * 16 + lm;
        float v = acc[mi][ni][r];
        if (EPI != 4) v += bias[col];
        if (EPI == 0) {  // qkv scatter: col = which*1024 + h*64 + d; bf16 outputs
          int which = col >> 10, rem = col & 1023, hh = rem >> 6, d = rem & 63;
          int bb = row >> 11, n = row & 2047;
          size_t bh = (size_t)(bb * HEADS + hh);
          ushort_t* o16 = (ushort_t*)outv;
          if (which == 0)
            o16[(bh * NTOK + n) * HDIM + d] = f2b(v * QSC);  // fold scale*log2e
          else if (which == 1)
            o16[QSZ + (bh * NTOK + n) * HDIM + d] = f2b(v);
          else
            o16[2 * QSZ + (bh * HDIM + d) * NTOK + n] = f2b(v);
        } else if (EPI == 2) {  // fc1 raw (GELU applied in LN kernel)
          ((ushort_t*)outv)[(size_t)row * HIDDEN + col] = f2b(v);
        } else {  // EPI==4: raw bf16 partial for split-K
          ((ushort_t*)outv)[(size_t)kz * MROWS * DIMC + (size_t)row * DIMC + col] = f2b(v);
        }
      }
    }
  }
}

// ---------------- combine proj partials: hb = bf16(2*(p0+p1+bias)) -----------
__global__ __launch_bounds__(256) void k_comb_proj(const ushort_t* __restrict__ p0,
                                                   const ushort_t* __restrict__ p1,
                                                   const float* __restrict__ bias,
                                                   ushort_t* __restrict__ hb) {
  int i = blockIdx.x * 256 + threadIdx.x;          // us4 index (4 elems)
  int colb = (i & 255) * 4;
  us4 a = ((const us4*)p0)[i];
  us4 b = ((const us4*)p1)[i];
  us4 o;
  o.x = f2b(2.f * (b2f(a.x) + b2f(b.x) + bias[colb + 0]));
  o.y = f2b(2.f * (b2f(a.y) + b2f(b.y) + bias[colb + 1]));
  o.z = f2b(2.f * (b2f(a.z) + b2f(b.z) + bias[colb + 2]));
  o.w = f2b(2.f * (b2f(a.w) + b2f(b.w) + bias[colb + 3]));
  ((us4*)hb)[i] = o;
}

// ------- combine fc2 partials + residual, transposed store to (B,C,N) --------
__global__ __launch_bounds__(256) void k_comb_fc2(const ushort_t* __restrict__ p0,
                                                  const ushort_t* __restrict__ p1,
                                                  const ushort_t* __restrict__ hb,
                                                  const float* __restrict__ bias,
                                                  float* __restrict__ out) {
  __shared__ float t[32][33];
  int b  = blockIdx.z;
  int c0 = blockIdx.y * 32, n0 = blockIdx.x * 32;
  int tx = threadIdx.x, ty = threadIdx.y;  // (32,8)
#pragma unroll
  for (int l = 0; l < 4; l++) {
    size_t idx = ((size_t)(b * NTOK + n0 + ty + l * 8)) * DIMC + c0 + tx;
    t[ty + l * 8][tx] = b2f(p0[idx]) + b2f(p1[idx]) + b2f(hb[idx]) + bias[c0 + tx];
  }
  __syncthreads();
#pragma unroll
  for (int l = 0; l < 4; l++)
    out[((size_t)(b * DIMC + c0 + ty + l * 8)) * NTOK + n0 + tx] = t[tx][ty + l * 8];
}

// ---------------- MFMA flash attention, fixed-max softmax_one ----------------
// out' = e^x/(1+Sum e^x) (max-sub dropped: ~2e-4 abs err; masked rows p=1
// exactly). Row-sum via ones-MFMA. q pre-scaled by SCALE*log2e. K/V double-
// buffered, one barrier per tile. (Round-0 structure — best measured 65.2us;
// setprio regressed, QBLK=64 regressed, 32x32 swapped-QK was parity, direct-
// L2 K/V regressed 2x. Staged-LDS 16x16 is the verified local optimum.)
__global__ __launch_bounds__(256) void k_attn_mfma(const ushort_t* __restrict__ qkv,
                                                   const int* __restrict__ mask,
                                                   ushort_t* __restrict__ scram) {
  __shared__ ushort_t Kl[2][64 * 64];
  __shared__ ushort_t Vl[2][64 * 64];
  __shared__ ushort_t Pl[4 * 32 * 72];
  const int tid = threadIdx.x;
  const int lane = tid & 63, w = tid >> 6;
  const int lm = lane & 15, quad = lane >> 4;
  const int bh = blockIdx.y, b = bh >> 4, h = bh & 15;
  const int q0 = blockIdx.x * 128 + w * 32;
  const ushort_t* qg  = qkv + (size_t)bh * NTOK * HDIM;
  const ushort_t* kg  = qkv + QSZ + (size_t)bh * NTOK * HDIM;
  const ushort_t* vTg = qkv + 2 * QSZ + (size_t)bh * HDIM * NTOK;
  ushort_t* Pw = &Pl[w * 32 * 72];

  const short8 ones = {0x3F80, 0x3F80, 0x3F80, 0x3F80, 0x3F80, 0x3F80, 0x3F80, 0x3F80};

  // Q fragments (A-layout): m=lm, k=hf*32+quad*8+j  — register-resident
  short8 qf[2][2];
#pragma unroll
  for (int qs = 0; qs < 2; qs++)
#pragma unroll
    for (int hf = 0; hf < 2; hf++)
      qf[qs][hf] = *(const short8*)&qg[(size_t)(q0 + qs * 16 + lm) * HDIM + hf * 32 + quad * 8];

  bool mk[2][4];
#pragma unroll
  for (int qs = 0; qs < 2; qs++)
#pragma unroll
    for (int r = 0; r < 4; r++)
      mk[qs][r] = mask[(size_t)bh * NTOK + q0 + qs * 16 + quad * 4 + r] != 0;

  f32x4 O[2][4], La[2];
#pragma unroll
  for (int qs = 0; qs < 2; qs++) {
    La[qs] = (f32x4){0.f, 0.f, 0.f, 0.f};
#pragma unroll
    for (int r = 0; r < 4; r++) O[qs][r] = (f32x4){0.f, 0.f, 0.f, 0.f};
  }

  // staging indices: slot s (16B) -> row s>>3, stores global chunk (s&7)^(row&7)
  const int s0 = tid, s1 = tid + 256;
  const int r0 = s0 >> 3, g0 = (s0 & 7) ^ (r0 & 7);
  const int r1 = s1 >> 3, g1 = (s1 & 7) ^ (r1 & 7);

  // preload tile 0 into buffer 0
  gl_lds16(kg + (size_t)r0 * HDIM + g0 * 8, &Kl[0][s0 * 8]);
  gl_lds16(kg + (size_t)r1 * HDIM + g1 * 8, &Kl[0][s1 * 8]);
  gl_lds16(vTg + (size_t)r0 * NTOK + g0 * 8, &Vl[0][s0 * 8]);
  gl_lds16(vTg + (size_t)r1 * NTOK + g1 * 8, &Vl[0][s1 * 8]);

  for (int kt = 0; kt < NTOK; kt += 64) {
    const int cur = (kt >> 6) & 1, nxt = cur ^ 1;
    __syncthreads();  // drains vmcnt: tile kt resident; prior tile's reads done
    if (kt + 64 < NTOK) {  // async-stage next tile; lands before next barrier
      gl_lds16(kg + (size_t)(kt + 64 + r0) * HDIM + g0 * 8, &Kl[nxt][s0 * 8]);
      gl_lds16(kg + (size_t)(kt + 64 + r1) * HDIM + g1 * 8, &Kl[nxt][s1 * 8]);
      gl_lds16(vTg + (size_t)r0 * NTOK + kt + 64 + g0 * 8, &Vl[nxt][s0 * 8]);
      gl_lds16(vTg + (size_t)r1 * NTOK + kt + 64 + g1 * 8, &Vl[nxt][s1 * 8]);
    }

    // K fragments (B-layout): n=key=ksub*16+lm, k=hf*32+quad*8+j
    short8 kf[4][2];
#pragma unroll
    for (int ksub = 0; ksub < 4; ksub++)
#pragma unroll
      for (int hf = 0; hf < 2; hf++)
        kf[ksub][hf] = *(const short8*)&Kl[cur][(ksub * 16 + lm) * 64 + ((4 * hf + quad) ^ (lm & 7)) * 8];

#pragma unroll
    for (int qs = 0; qs < 2; qs++) {
      f32x4 S[4];
#pragma unroll
      for (int ksub = 0; ksub < 4; ksub++) {
        S[ksub] = (f32x4){0.f, 0.f, 0.f, 0.f};
        S[ksub] = __builtin_amdgcn_mfma_f32_16x16x32_bf16(qf[qs][0], kf[ksub][0], S[ksub], 0, 0, 0);
        S[ksub] = __builtin_amdgcn_mfma_f32_16x16x32_bf16(qf[qs][1], kf[ksub][1], S[ksub], 0, 0, 0);
      }
      // p = exp2(s) (q pre-scaled); masked rows: p = 1 exactly. Truncation cvt.
#pragma unroll
      for (int r = 0; r < 4; r++) {
        const int prow = qs * 16 + quad * 4 + r;
#pragma unroll
        for (int ksub = 0; ksub < 4; ksub++) {
          float p = mk[qs][r] ? fexp2(S[ksub][r]) : 1.0f;
          Pw[prow * 72 + ksub * 16 + lm] = (ushort_t)(__float_as_uint(p) >> 16);
        }
      }
    }
    __builtin_amdgcn_s_waitcnt(0xC07F);  // drain P ds_writes (same-wave RAW)

    // V fragments (B-layout): n=d=dsub*16+lm, k=key=hf*32+quad*8+j from vT LDS
    short8 vf[4][2];
#pragma unroll
    for (int dsub = 0; dsub < 4; dsub++)
#pragma unroll
      for (int hf = 0; hf < 2; hf++)
        vf[dsub][hf] = *(const short8*)&Vl[cur][(dsub * 16 + lm) * 64 + ((4 * hf + quad) ^ (lm & 7)) * 8];

#pragma unroll
    for (int qs = 0; qs < 2; qs++) {
      short8 pf[2];
#pragma unroll
      for (int hf = 0; hf < 2; hf++)
        pf[hf] = *(const short8*)&Pw[(qs * 16 + lm) * 72 + hf * 32 + quad * 8];
#pragma unroll
      for (int dsub = 0; dsub < 4; dsub++) {
        O[qs][dsub] = __builtin_amdgcn_mfma_f32_16x16x32_bf16(pf[0], vf[dsub][0], O[qs][dsub], 0, 0, 0);
        O[qs][dsub] = __builtin_amdgcn_mfma_f32_16x16x32_bf16(pf[1], vf[dsub][1], O[qs][dsub], 0, 0, 0);
      }
      La[qs] = __builtin_amdgcn_mfma_f32_16x16x32_bf16(pf[0], ones, La[qs], 0, 0, 0);
      La[qs] = __builtin_amdgcn_mfma_f32_16x16x32_bf16(pf[1], ones, La[qs], 0, 0, 0);
    }
  }

  // epilogue: /(1+l), scrambled merge (b,h,n,d) -> row d*32+h*2+(n>>10), col n&1023
#pragma unroll
  for (int qs = 0; qs < 2; qs++)
#pragma unroll
    for (int r = 0; r < 4; r++) {
      int n = q0 + qs * 16 + quad * 4 + r;
      float inv = 1.f / (1.f + La[qs][r]);
      int n1 = n >> 10, nn0 = n & 1023;
#pragma unroll
      for (int dsub = 0; dsub < 4; dsub++) {
        int d = dsub * 16 + lm;
        int np = d * 32 + h * 2 + n1;
        scram[((size_t)(b * NTOK + np)) * DIMC + nn0] = f2b(O[qs][dsub][r] * inv);
      }
    }
}

// ---------------- GELU (exact, erf) + row LayerNorm over HIDDEN=4096 ---------
__global__ __launch_bounds__(256) void k_ln(ushort_t* __restrict__ mid,
                                            const float* __restrict__ g,
                                            const float* __restrict__ bta) {
  const int row = blockIdx.x;
  ushort_t* p = mid + (size_t)row * HIDDEN;
  const int tid = threadIdx.x;
  float lv[16];
  float s = 0.f, s2 = 0.f;
#pragma unroll
  for (int i = 0; i < 4; i++) {
    us4 u = *(const us4*)&p[tid * 4 + i * 1024];
#pragma unroll
    for (int j = 0; j < 4; j++) {
      float xx = b2f((j == 0) ? u.x : (j == 1) ? u.y : (j == 2) ? u.z : u.w);
      xx = 0.5f * xx * (1.f + erff(xx * 0.70710678118654752f));  // exact GELU
      lv[i * 4 + j] = xx;
      s += xx;
      s2 += xx * xx;
    }
  }
#pragma unroll
  for (int off = 32; off > 0; off >>= 1) {
    s += __shfl_down(s, off);
    s2 += __shfl_down(s2, off);
  }
  __shared__ float rs[4], rs2[4];
  if ((tid & 63) == 0) { rs[tid >> 6] = s; rs2[tid >> 6] = s2; }
  __syncthreads();
  float ts = rs[0] + rs[1] + rs[2] + rs[3];
  float ts2 = rs2[0] + rs2[1] + rs2[2] + rs2[3];
  float mu = ts * (1.f / HIDDEN);
  float var = ts2 * (1.f / HIDDEN) - mu * mu;
  float rstd = rsqrtf(var + 1e-5f);
#pragma unroll
  for (int i = 0; i < 4; i++) {
    us4 o;
#pragma unroll
    for (int j = 0; j < 4; j++) {
      int f = tid * 4 + i * 1024 + j;
      float y = (lv[i * 4 + j] - mu) * rstd * g[f] + bta[f];
      ushort_t ob = f2b(y);
      if (j == 0) o.x = ob; else if (j == 1) o.y = ob; else if (j == 2) o.z = ob; else o.w = ob;
    }
    *(us4*)&p[tid * 4 + i * 1024] = o;
  }
}

extern "C" void kernel_launch(void* const* d_in, const int* in_sizes, int n_in,
                              void* d_out, int out_size, void* d_ws, size_t ws_size,
                              hipStream_t stream) {
  const float* x      = (const float*)d_in[0];
  const int*   mask   = (const int*)d_in[1];
  const float* qkv_w  = (const float*)d_in[2];
  const float* qkv_b  = (const float*)d_in[3];
  const float* proj_w = (const float*)d_in[4];
  const float* proj_b = (const float*)d_in[5];
  const float* fc1_w  = (const float*)d_in[6];
  const float* fc1_b  = (const float*)d_in[7];
  const float* ln_g   = (const float*)d_in[8];
  const float* ln_b   = (const float*)d_in[9];
  const float* fc2_w  = (const float*)d_in[10];
  const float* fc2_b  = (const float*)d_in[11];

  char* w = (char*)d_ws;
  ushort_t* qkv16  = (ushort_t*)w;           w += 3 * QSZ * 2;                    // 25.2 MB
  ushort_t* xtb    = (ushort_t*)w;           w += (size_t)MROWS * DIMC * 2;       //  8.4 MB
  ushort_t* scramb = (ushort_t*)w;           w += (size_t)MROWS * DIMC * 2;       //  8.4 MB
  ushort_t* hb     = (ushort_t*)w;           w += (size_t)MROWS * DIMC * 2;       //  8.4 MB
  ushort_t* mid    = (ushort_t*)w;           w += (size_t)MROWS * HIDDEN * 2;     // 33.6 MB
  ushort_t* wqkvb  = (ushort_t*)w;           w += (size_t)3 * DIMC * DIMC * 2;    //  6.3 MB
  ushort_t* wprojb = (ushort_t*)w;           w += (size_t)DIMC * DIMC * 2;        //  2.1 MB
  ushort_t* wfc1b  = (ushort_t*)w;           w += (size_t)HIDDEN * DIMC * 2;      //  8.4 MB
  ushort_t* wfc2b  = (ushort_t*)w;           w += (size_t)DIMC * HIDDEN * 2;      //  8.4 MB
  ushort_t* pbuf   = (ushort_t*)w;           w += (size_t)2 * MROWS * DIMC * 2;   // 16.8 MB (bf16 partials)
  ushort_t* pbuf1  = pbuf + (size_t)MROWS * DIMC;

  k_pre<<<dim3(4096 + 12288), 256, 0, stream>>>(x, qkv_w, proj_w, fc1_w, fc2_w,
                                                xtb, wqkvb, wprojb, wfc1b, wfc2b);

  // 1D grids: (ntx*nty) with ntx = cols/128 (divisible by 8), nty = rows/128
  k_gemm_bf16<0, 3, DIMC, DIMC><<<dim3(24 * 32), 256, 0, stream>>>(
      xtb, wqkvb, qkv_b, qkv16);
  k_attn_mfma<<<dim3(NTOK / 128, BATCH * HEADS), 256, 0, stream>>>(
      qkv16, mask, scramb);
  // proj: split-K=2 (K=1024 -> 2x512), bf16 partials, combine adds bias & x2
  k_gemm_bf16<4, 1, DIMC, 512><<<dim3(8 * 32, 2), 256, 0, stream>>>(
      scramb, wprojb, nullptr, pbuf);
  k_comb_proj<<<dim3(4096), 256, 0, stream>>>(pbuf, pbuf1, proj_b, hb);
  k_gemm_bf16<2, 4, DIMC, DIMC><<<dim3(32 * 32), 256, 0, stream>>>(
      hb, wfc1b, fc1_b, mid);
  k_ln<<<dim3(MROWS), 256, 0, stream>>>(mid, ln_g, ln_b);
  // fc2: split-K=2 (K=4096 -> 2x2048), combine adds bias+residual, transposes
  k_gemm_bf16<4, 1, HIDDEN, 2048><<<dim3(8 * 32, 2), 256, 0, stream>>>(
      mid, wfc2b, nullptr, pbuf);
  k_comb_fc2<<<dim3(NTOK / 32, DIMC / 32, BATCH), dim3(32, 8), 0, stream>>>(
      pbuf, pbuf1, hb, fc2_b, (float*)d_out);
}

// Round 10
// 360.369 us; speedup vs baseline: 1.0869x; 1.0449x over previous
//
#include <hip/hip_runtime.h>
#include <math.h>

#define DIMC   1024
#define NTOK   2048
#define BATCH  2
#define HEADS  16
#define HDIM   64
#define HIDDEN 4096
#define MROWS  (BATCH*NTOK)                      /* 4096 token-rows */
#define QSZ    ((size_t)BATCH*HEADS*NTOK*HDIM)   /* 4194304 */
#define QSC    0.18033688f                       /* 64^-0.5 * log2(e), folded into q */

typedef unsigned short ushort_t;
typedef __attribute__((ext_vector_type(8))) short short8;
typedef __attribute__((ext_vector_type(4))) float f32x4;
typedef __attribute__((ext_vector_type(4))) unsigned short us4;

__device__ __forceinline__ ushort_t f2b(float f) {
  union { float f; unsigned int u; } cv; cv.f = f;
  unsigned int u = cv.u;
  unsigned int r = (u + 0x7fffu + ((u >> 16) & 1u)) >> 16;  // RNE
  return (ushort_t)r;
}

__device__ __forceinline__ float b2f(ushort_t b) {
  union { unsigned int u; float f; } cv; cv.u = ((unsigned int)b) << 16;
  return cv.f;
}

__device__ __forceinline__ float fexp2(float x) {
#if __has_builtin(__builtin_amdgcn_exp2f)
  return __builtin_amdgcn_exp2f(x);
#else
  return exp2f(x);
#endif
}

__device__ __forceinline__ void gl_lds16(const void* g, void* l) {
  __builtin_amdgcn_global_load_lds(
      (const __attribute__((address_space(1))) void*)g,
      (__attribute__((address_space(3))) void*)l, 16, 0, 0);
}

// ---- fused pre-pass: transpose x (B,C,N)->xt (B,N,C) bf16  +  w fp32->bf16 --
// blocks [0,4096): transpose tiles; [4096,16384): weight convert (one launch
// instead of two -> one fewer inter-kernel gap).
__global__ __launch_bounds__(256) void k_pre(const float* __restrict__ x,
                                             const float* __restrict__ w0,
                                             const float* __restrict__ w1,
                                             const float* __restrict__ w2,
                                             const float* __restrict__ w3,
                                             ushort_t* __restrict__ xt,
                                             ushort_t* __restrict__ o0,
                                             ushort_t* __restrict__ o1,
                                             ushort_t* __restrict__ o2,
                                             ushort_t* __restrict__ o3) {
  __shared__ float t[32][33];
  int bid = blockIdx.x;
  if (bid < 4096) {  // transpose path
    int b   = bid >> 11;          // 2048 tiles per batch
    int rem = bid & 2047;
    int n0  = (rem & 63) * 32;    // 64 n-tiles
    int c0  = (rem >> 6) * 32;    // 32 c-tiles
    int tx = threadIdx.x & 31, ty = threadIdx.x >> 5;  // (32,8)
#pragma unroll
    for (int l = 0; l < 4; l++)
      t[ty + l * 8][tx] = x[((size_t)(b * DIMC + c0 + ty + l * 8)) * NTOK + n0 + tx];
    __syncthreads();
#pragma unroll
    for (int l = 0; l < 4; l++)
      xt[((size_t)(b * NTOK + n0 + ty + l * 8)) * DIMC + c0 + tx] = f2b(t[tx][ty + l * 8]);
  } else {  // weight-convert path
    int cb = bid - 4096;
    const float* in; ushort_t* out; int base;
    if (cb < 3072)      { in = w0; out = o0; base = cb; }
    else if (cb < 4096) { in = w1; out = o1; base = cb - 3072; }
    else if (cb < 8192) { in = w2; out = o2; base = cb - 4096; }
    else                { in = w3; out = o3; base = cb - 8192; }
    int i = base * 256 + threadIdx.x;
    float4 v = ((const float4*)in)[i];
    us4 o; o.x = f2b(v.x); o.y = f2b(v.y); o.z = f2b(v.z); o.w = f2b(v.w);
    ((us4*)out)[i] = o;
  }
}

// ---------------- bf16 MFMA GEMM: out = A(MxK) @ W(NcolsxK)^T + bias ---------
// 128x128 tile, 4 waves x 64x64, 16x16x32 MFMA. Direct global_load_lds
// staging (m97 structure): LDS is lane-linear, swizzle pre-applied on the
// GLOBAL source chunk (gch), fragment reads undo it (sw8). Double-buffered,
// one __syncthreads per 32-K step (drains vmcnt -> staged tile visible).
// XCD-aware 1D grid on blockIdx.x. Split-K via blockIdx.y (kz) — 2-way only:
// 4-way measured -7us (doubles partial round-trip, halves K-loop amortization).
// XROW: XCD owns ROW-tile groups (A-panel L2-resident, W streams) — use when
// A is the bigger matrix (fc2: cuts per-XCD L3 stream 269->67MB; proj, qkv).
// XROW=0: XCD owns COL groups (W-panel resident) — fc1 (symmetric).
// EPI: 0 = qkv -> bf16 q(*QSC)/k/vT scatter, 2 = fc1 raw bf16 (GELU in LN),
//      4 = raw bf16 partial (no bias) at outv + kz*MROWS*DIMC
template <int EPI, int NTX8, int KSTRIDE, int KLEN, int XROW>
__global__ __launch_bounds__(256) void k_gemm_bf16(const ushort_t* __restrict__ A,
                                                   const ushort_t* __restrict__ W,
                                                   const float* __restrict__ bias,
                                                   void* __restrict__ outv) {
  __shared__ ushort_t As[2][128 * 32];
  __shared__ ushort_t Bs[2][128 * 32];
  const int tid = threadIdx.x;
  const int lane = tid & 63, wv = tid >> 6;
  const int bid = blockIdx.x, kz = blockIdx.y;
  const int xcd = bid & 7, t = bid >> 3;
  const int row0 = XROW ? (xcd * NTX8 + (t % NTX8)) * 128 : (t / NTX8) * 128;
  const int col0 = XROW ? (t / NTX8) * 128 : (xcd * NTX8 + (t % NTX8)) * 128;
  const int wrow0 = (wv >> 1) * 64, wcol0 = (wv & 1) * 64;
  const int lm = lane & 15, lq = lane >> 4;
  const int srow = wv * 32 + (lane >> 2);              // global row this lane stages
  const int gch = (lane & 3) ^ ((lane >> 3) & 3);      // swizzled global chunk
  const int sw8 = (lq ^ ((lm >> 1) & 3)) * 8;          // fragment read slot

  const ushort_t* Ab = A + (size_t)(row0 + srow) * KSTRIDE + (size_t)kz * KLEN + gch * 8;
  const ushort_t* Wb = W + (size_t)(col0 + srow) * KSTRIDE + (size_t)kz * KLEN + gch * 8;
  const size_t rstep = (size_t)16 * KSTRIDE;

  f32x4 acc[4][4];
#pragma unroll
  for (int i = 0; i < 4; i++)
#pragma unroll
    for (int j = 0; j < 4; j++) acc[i][j] = (f32x4){0.f, 0.f, 0.f, 0.f};

  // dest: wave-uniform base; HW scatters lane*16B -> byte wv*2048 + lane*16,
  // which is exactly row srow (=wv*32+lane>>2), slot (lane&3) of the old layout.
#define STAGE(buf, k0) do {                                      \
    gl_lds16(Ab + (k0),         &As[buf][wv * 1024]);            \
    gl_lds16(Ab + rstep + (k0), &As[buf][wv * 1024 + 512]);      \
    gl_lds16(Wb + (k0),         &Bs[buf][wv * 1024]);            \
    gl_lds16(Wb + rstep + (k0), &Bs[buf][wv * 1024 + 512]);      \
  } while (0)

  auto compute = [&](int buf) {
    short8 af[4], bf[4];
#pragma unroll
    for (int mi = 0; mi < 4; mi++)
      af[mi] = *(const short8*)&As[buf][(wrow0 + mi * 16 + lm) * 32 + sw8];
#pragma unroll
    for (int ni = 0; ni < 4; ni++)
      bf[ni] = *(const short8*)&Bs[buf][(wcol0 + ni * 16 + lm) * 32 + sw8];
#pragma unroll
    for (int mi = 0; mi < 4; mi++)
#pragma unroll
      for (int ni = 0; ni < 4; ni++)
        acc[mi][ni] = __builtin_amdgcn_mfma_f32_16x16x32_bf16(af[mi], bf[ni], acc[mi][ni], 0, 0, 0);
  };

  constexpr int S = KLEN / 32;
  STAGE(0, 0);                                   // prologue: tile 0 -> buf 0
#pragma unroll 1
  for (int kk = 0; kk < S; kk++) {
    __syncthreads();                             // drains vmcnt: tile kk resident;
                                                 // prev compute's ds_reads done
    if (kk + 1 < S) STAGE((kk + 1) & 1, (kk + 1) * 32);  // prefetch overlaps MFMA
    compute(kk & 1);
  }
#undef STAGE

#pragma unroll
  for (int mi = 0; mi < 4; mi++) {
#pragma unroll
    for (int ni = 0; ni < 4; ni++) {
#pragma unroll
      for (int r = 0; r < 4; r++) {
        const int row = row0 + wrow0 + mi * 16 + lq * 4 + r;
        const int col = col0 + wcol0 + ni * 16 + lm;
        float v = acc[mi][ni][r];
        if (EPI != 4) v += bias[col];
        if (EPI == 0) {  // qkv scatter: col = which*1024 + h*64 + d; bf16 outputs
          int which = col >> 10, rem = col & 1023, hh = rem >> 6, d = rem & 63;
          int bb = row >> 11, n = row & 2047;
          size_t bh = (size_t)(bb * HEADS + hh);
          ushort_t* o16 = (ushort_t*)outv;
          if (which == 0)
            o16[(bh * NTOK + n) * HDIM + d] = f2b(v * QSC);  // fold scale*log2e
          else if (which == 1)
            o16[QSZ + (bh * NTOK + n) * HDIM + d] = f2b(v);
          else
            o16[2 * QSZ + (bh * HDIM + d) * NTOK + n] = f2b(v);
        } else if (EPI == 2) {  // fc1 raw (GELU applied in LN kernel)
          ((ushort_t*)outv)[(size_t)row * HIDDEN + col] = f2b(v);
        } else {  // EPI==4: raw bf16 partial for split-K
          ((ushort_t*)outv)[(size_t)kz * MROWS * DIMC + (size_t)row * DIMC + col] = f2b(v);
        }
      }
    }
  }
}

// ---------------- combine proj partials: hb = bf16(2*(p0+p1+bias)) -----------
__global__ __launch_bounds__(256) void k_comb_proj(const ushort_t* __restrict__ p0,
                                                   const ushort_t* __restrict__ p1,
                                                   const float* __restrict__ bias,
                                                   ushort_t* __restrict__ hb) {
  int i = blockIdx.x * 256 + threadIdx.x;          // us4 index (4 elems)
  int colb = (i & 255) * 4;
  us4 a = ((const us4*)p0)[i];
  us4 b = ((const us4*)p1)[i];
  us4 o;
  o.x = f2b(2.f * (b2f(a.x) + b2f(b.x) + bias[colb + 0]));
  o.y = f2b(2.f * (b2f(a.y) + b2f(b.y) + bias[colb + 1]));
  o.z = f2b(2.f * (b2f(a.z) + b2f(b.z) + bias[colb + 2]));
  o.w = f2b(2.f * (b2f(a.w) + b2f(b.w) + bias[colb + 3]));
  ((us4*)hb)[i] = o;
}

// ------- combine fc2 partials + residual, transposed store to (B,C,N) --------
__global__ __launch_bounds__(256) void k_comb_fc2(const ushort_t* __restrict__ p0,
                                                  const ushort_t* __restrict__ p1,
                                                  const ushort_t* __restrict__ hb,
                                                  const float* __restrict__ bias,
                                                  float* __restrict__ out) {
  __shared__ float t[32][33];
  int b  = blockIdx.z;
  int c0 = blockIdx.y * 32, n0 = blockIdx.x * 32;
  int tx = threadIdx.x, ty = threadIdx.y;  // (32,8)
#pragma unroll
  for (int l = 0; l < 4; l++) {
    size_t idx = ((size_t)(b * NTOK + n0 + ty + l * 8)) * DIMC + c0 + tx;
    t[ty + l * 8][tx] = b2f(p0[idx]) + b2f(p1[idx]) + b2f(hb[idx]) + bias[c0 + tx];
  }
  __syncthreads();
#pragma unroll
  for (int l = 0; l < 4; l++)
    out[((size_t)(b * DIMC + c0 + ty + l * 8)) * NTOK + n0 + tx] = t[tx][ty + l * 8];
}

// ---------------- MFMA flash attention, fixed-max softmax_one ----------------
// out' = e^x/(1+Sum e^x) (max-sub dropped: ~2e-4 abs err; masked rows p=1
// exactly). Row-sum via ones-MFMA. q pre-scaled by SCALE*log2e. K/V double-
// buffered, one barrier per tile. (Round-0 structure — best measured 65.2us;
// setprio regressed, QBLK=64 regressed, 32x32 swapped-QK was parity, direct-
// L2 K/V regressed 2x. Staged-LDS 16x16 is the verified local optimum.)
__global__ __launch_bounds__(256) void k_attn_mfma(const ushort_t* __restrict__ qkv,
                                                   const int* __restrict__ mask,
                                                   ushort_t* __restrict__ scram) {
  __shared__ ushort_t Kl[2][64 * 64];
  __shared__ ushort_t Vl[2][64 * 64];
  __shared__ ushort_t Pl[4 * 32 * 72];
  const int tid = threadIdx.x;
  const int lane = tid & 63, w = tid >> 6;
  const int lm = lane & 15, quad = lane >> 4;
  const int bh = blockIdx.y, b = bh >> 4, h = bh & 15;
  const int q0 = blockIdx.x * 128 + w * 32;
  const ushort_t* qg  = qkv + (size_t)bh * NTOK * HDIM;
  const ushort_t* kg  = qkv + QSZ + (size_t)bh * NTOK * HDIM;
  const ushort_t* vTg = qkv + 2 * QSZ + (size_t)bh * HDIM * NTOK;
  ushort_t* Pw = &Pl[w * 32 * 72];

  const short8 ones = {0x3F80, 0x3F80, 0x3F80, 0x3F80, 0x3F80, 0x3F80, 0x3F80, 0x3F80};

  // Q fragments (A-layout): m=lm, k=hf*32+quad*8+j  — register-resident
  short8 qf[2][2];
#pragma unroll
  for (int qs = 0; qs < 2; qs++)
#pragma unroll
    for (int hf = 0; hf < 2; hf++)
      qf[qs][hf] = *(const short8*)&qg[(size_t)(q0 + qs * 16 + lm) * HDIM + hf * 32 + quad * 8];

  bool mk[2][4];
#pragma unroll
  for (int qs = 0; qs < 2; qs++)
#pragma unroll
    for (int r = 0; r < 4; r++)
      mk[qs][r] = mask[(size_t)bh * NTOK + q0 + qs * 16 + quad * 4 + r] != 0;

  f32x4 O[2][4], La[2];
#pragma unroll
  for (int qs = 0; qs < 2; qs++) {
    La[qs] = (f32x4){0.f, 0.f, 0.f, 0.f};
#pragma unroll
    for (int r = 0; r < 4; r++) O[qs][r] = (f32x4){0.f, 0.f, 0.f, 0.f};
  }

  // staging indices: slot s (16B) -> row s>>3, stores global chunk (s&7)^(row&7)
  const int s0 = tid, s1 = tid + 256;
  const int r0 = s0 >> 3, g0 = (s0 & 7) ^ (r0 & 7);
  const int r1 = s1 >> 3, g1 = (s1 & 7) ^ (r1 & 7);

  // preload tile 0 into buffer 0
  gl_lds16(kg + (size_t)r0 * HDIM + g0 * 8, &Kl[0][s0 * 8]);
  gl_lds16(kg + (size_t)r1 * HDIM + g1 * 8, &Kl[0][s1 * 8]);
  gl_lds16(vTg + (size_t)r0 * NTOK + g0 * 8, &Vl[0][s0 * 8]);
  gl_lds16(vTg + (size_t)r1 * NTOK + g1 * 8, &Vl[0][s1 * 8]);

  for (int kt = 0; kt < NTOK; kt += 64) {
    const int cur = (kt >> 6) & 1, nxt = cur ^ 1;
    __syncthreads();  // drains vmcnt: tile kt resident; prior tile's reads done
    if (kt + 64 < NTOK) {  // async-stage next tile; lands before next barrier
      gl_lds16(kg + (size_t)(kt + 64 + r0) * HDIM + g0 * 8, &Kl[nxt][s0 * 8]);
      gl_lds16(kg + (size_t)(kt + 64 + r1) * HDIM + g1 * 8, &Kl[nxt][s1 * 8]);
      gl_lds16(vTg + (size_t)r0 * NTOK + kt + 64 + g0 * 8, &Vl[nxt][s0 * 8]);
      gl_lds16(vTg + (size_t)r1 * NTOK + kt + 64 + g1 * 8, &Vl[nxt][s1 * 8]);
    }

    // K fragments (B-layout): n=key=ksub*16+lm, k=hf*32+quad*8+j
    short8 kf[4][2];
#pragma unroll
    for (int ksub = 0; ksub < 4; ksub++)
#pragma unroll
      for (int hf = 0; hf < 2; hf++)
        kf[ksub][hf] = *(const short8*)&Kl[cur][(ksub * 16 + lm) * 64 + ((4 * hf + quad) ^ (lm & 7)) * 8];

#pragma unroll
    for (int qs = 0; qs < 2; qs++) {
      f32x4 S[4];
#pragma unroll
      for (int ksub = 0; ksub < 4; ksub++) {
        S[ksub] = (f32x4){0.f, 0.f, 0.f, 0.f};
        S[ksub] = __builtin_amdgcn_mfma_f32_16x16x32_bf16(qf[qs][0], kf[ksub][0], S[ksub], 0, 0, 0);
        S[ksub] = __builtin_amdgcn_mfma_f32_16x16x32_bf16(qf[qs][1], kf[ksub][1], S[ksub], 0, 0, 0);
      }
      // p = exp2(s) (q pre-scaled); masked rows: p = 1 exactly. Truncation cvt.
#pragma unroll
      for (int r = 0; r < 4; r++) {
        const int prow = qs * 16 + quad * 4 + r;
#pragma unroll
        for (int ksub = 0; ksub < 4; ksub++) {
          float p = mk[qs][r] ? fexp2(S[ksub][r]) : 1.0f;
          Pw[prow * 72 + ksub * 16 + lm] = (ushort_t)(__float_as_uint(p) >> 16);
        }
      }
    }
    __builtin_amdgcn_s_waitcnt(0xC07F);  // drain P ds_writes (same-wave RAW)

    // V fragments (B-layout): n=d=dsub*16+lm, k=key=hf*32+quad*8+j from vT LDS
    short8 vf[4][2];
#pragma unroll
    for (int dsub = 0; dsub < 4; dsub++)
#pragma unroll
      for (int hf = 0; hf < 2; hf++)
        vf[dsub][hf] = *(const short8*)&Vl[cur][(dsub * 16 + lm) * 64 + ((4 * hf + quad) ^ (lm & 7)) * 8];

#pragma unroll
    for (int qs = 0; qs < 2; qs++) {
      short8 pf[2];
#pragma unroll
      for (int hf = 0; hf < 2; hf++)
        pf[hf] = *(const short8*)&Pw[(qs * 16 + lm) * 72 + hf * 32 + quad * 8];
#pragma unroll
      for (int dsub = 0; dsub < 4; dsub++) {
        O[qs][dsub] = __builtin_amdgcn_mfma_f32_16x16x32_bf16(pf[0], vf[dsub][0], O[qs][dsub], 0, 0, 0);
        O[qs][dsub] = __builtin_amdgcn_mfma_f32_16x16x32_bf16(pf[1], vf[dsub][1], O[qs][dsub], 0, 0, 0);
      }
      La[qs] = __builtin_amdgcn_mfma_f32_16x16x32_bf16(pf[0], ones, La[qs], 0, 0, 0);
      La[qs] = __builtin_amdgcn_mfma_f32_16x16x32_bf16(pf[1], ones, La[qs], 0, 0, 0);
    }
  }

  // epilogue: /(1+l), scrambled merge (b,h,n,d) -> row d*32+h*2+(n>>10), col n&1023
#pragma unroll
  for (int qs = 0; qs < 2; qs++)
#pragma unroll
    for (int r = 0; r < 4; r++) {
      int n = q0 + qs * 16 + quad * 4 + r;
      float inv = 1.f / (1.f + La[qs][r]);
      int n1 = n >> 10, nn0 = n & 1023;
#pragma unroll
      for (int dsub = 0; dsub < 4; dsub++) {
        int d = dsub * 16 + lm;
        int np = d * 32 + h * 2 + n1;
        scram[((size_t)(b * NTOK + np)) * DIMC + nn0] = f2b(O[qs][dsub][r] * inv);
      }
    }
}

// ---------------- GELU (exact, erf) + row LayerNorm over HIDDEN=4096 ---------
__global__ __launch_bounds__(256) void k_ln(ushort_t* __restrict__ mid,
                                            const float* __restrict__ g,
                                            const float* __restrict__ bta) {
  const int row = blockIdx.x;
  ushort_t* p = mid + (size_t)row * HIDDEN;
  const int tid = threadIdx.x;
  float lv[16];
  float s = 0.f, s2 = 0.f;
#pragma unroll
  for (int i = 0; i < 4; i++) {
    us4 u = *(const us4*)&p[tid * 4 + i * 1024];
#pragma unroll
    for (int j = 0; j < 4; j++) {
      float xx = b2f((j == 0) ? u.x : (j == 1) ? u.y : (j == 2) ? u.z : u.w);
      xx = 0.5f * xx * (1.f + erff(xx * 0.70710678118654752f));  // exact GELU
      lv[i * 4 + j] = xx;
      s += xx;
      s2 += xx * xx;
    }
  }
#pragma unroll
  for (int off = 32; off > 0; off >>= 1) {
    s += __shfl_down(s, off);
    s2 += __shfl_down(s2, off);
  }
  __shared__ float rs[4], rs2[4];
  if ((tid & 63) == 0) { rs[tid >> 6] = s; rs2[tid >> 6] = s2; }
  __syncthreads();
  float ts = rs[0] + rs[1] + rs[2] + rs[3];
  float ts2 = rs2[0] + rs2[1] + rs2[2] + rs2[3];
  float mu = ts * (1.f / HIDDEN);
  float var = ts2 * (1.f / HIDDEN) - mu * mu;
  float rstd = rsqrtf(var + 1e-5f);
#pragma unroll
  for (int i = 0; i < 4; i++) {
    us4 o;
#pragma unroll
    for (int j = 0; j < 4; j++) {
      int f = tid * 4 + i * 1024 + j;
      float y = (lv[i * 4 + j] - mu) * rstd * g[f] + bta[f];
      ushort_t ob = f2b(y);
      if (j == 0) o.x = ob; else if (j == 1) o.y = ob; else if (j == 2) o.z = ob; else o.w = ob;
    }
    *(us4*)&p[tid * 4 + i * 1024] = o;
  }
}

extern "C" void kernel_launch(void* const* d_in, const int* in_sizes, int n_in,
                              void* d_out, int out_size, void* d_ws, size_t ws_size,
                              hipStream_t stream) {
  const float* x      = (const float*)d_in[0];
  const int*   mask   = (const int*)d_in[1];
  const float* qkv_w  = (const float*)d_in[2];
  const float* qkv_b  = (const float*)d_in[3];
  const float* proj_w = (const float*)d_in[4];
  const float* proj_b = (const float*)d_in[5];
  const float* fc1_w  = (const float*)d_in[6];
  const float* fc1_b  = (const float*)d_in[7];
  const float* ln_g   = (const float*)d_in[8];
  const float* ln_b   = (const float*)d_in[9];
  const float* fc2_w  = (const float*)d_in[10];
  const float* fc2_b  = (const float*)d_in[11];

  char* w = (char*)d_ws;
  ushort_t* qkv16  = (ushort_t*)w;           w += 3 * QSZ * 2;                    // 25.2 MB
  ushort_t* xtb    = (ushort_t*)w;           w += (size_t)MROWS * DIMC * 2;       //  8.4 MB
  ushort_t* scramb = (ushort_t*)w;           w += (size_t)MROWS * DIMC * 2;       //  8.4 MB
  ushort_t* hb     = (ushort_t*)w;           w += (size_t)MROWS * DIMC * 2;       //  8.4 MB
  ushort_t* mid    = (ushort_t*)w;           w += (size_t)MROWS * HIDDEN * 2;     // 33.6 MB
  ushort_t* wqkvb  = (ushort_t*)w;           w += (size_t)3 * DIMC * DIMC * 2;    //  6.3 MB
  ushort_t* wprojb = (ushort_t*)w;           w += (size_t)DIMC * DIMC * 2;        //  2.1 MB
  ushort_t* wfc1b  = (ushort_t*)w;           w += (size_t)HIDDEN * DIMC * 2;      //  8.4 MB
  ushort_t* wfc2b  = (ushort_t*)w;           w += (size_t)DIMC * HIDDEN * 2;      //  8.4 MB
  ushort_t* pbuf   = (ushort_t*)w;           w += (size_t)2 * MROWS * DIMC * 2;   // 16.8 MB (bf16 partials)
  ushort_t* pbuf1  = pbuf + (size_t)MROWS * DIMC;

  k_pre<<<dim3(4096 + 12288), 256, 0, stream>>>(x, qkv_w, proj_w, fc1_w, fc2_w,
                                                xtb, wqkvb, wprojb, wfc1b, wfc2b);

  // qkv: XROW (A-panel per XCD = 1MB L2-resident; W streams 50MB vs A 67MB)
  k_gemm_bf16<0, 4, DIMC, DIMC, 1><<<dim3(24 * 32), 256, 0, stream>>>(
      xtb, wqkvb, qkv_b, qkv16);
  k_attn_mfma<<<dim3(NTOK / 128, BATCH * HEADS), 256, 0, stream>>>(
      qkv16, mask, scramb);
  // proj: split-K=2, bf16 partials; XROW (A-panel resident, W 2.1MB streams)
  k_gemm_bf16<4, 4, DIMC, 512, 1><<<dim3(8 * 32, 2), 256, 0, stream>>>(
      scramb, wprojb, nullptr, pbuf);
  k_comb_proj<<<dim3(4096), 256, 0, stream>>>(pbuf, pbuf1, proj_b, hb);
  // fc1: symmetric (A=W=8.4MB) — keep col-ownership
  k_gemm_bf16<2, 4, DIMC, DIMC, 0><<<dim3(32 * 32), 256, 0, stream>>>(
      hb, wfc1b, fc1_b, mid);
  k_ln<<<dim3(MROWS), 256, 0, stream>>>(mid, ln_g, ln_b);
  // fc2: split-K=2; XROW (A=mid 33.6MB: per-XCD L3 stream 269->67MB)
  k_gemm_bf16<4, 4, HIDDEN, 2048, 1><<<dim3(8 * 32, 2), 256, 0, stream>>>(
      mid, wfc2b, nullptr, pbuf);
  k_comb_fc2<<<dim3(NTOK / 32, DIMC / 32, BATCH), dim3(32, 8), 0, stream>>>(
      pbuf, pbuf1, hb, fc2_b, (float*)d_out);
}

// Round 11
// 344.427 us; speedup vs baseline: 1.1372x; 1.0463x over previous
//
#include <hip/hip_runtime.h>
#include <math.h>

#define DIMC   1024
#define NTOK   2048
#define BATCH  2
#define HEADS  16
#define HDIM   64
#define HIDDEN 4096
#define MROWS  (BATCH*NTOK)                      /* 4096 token-rows */
#define QSZ    ((size_t)BATCH*HEADS*NTOK*HDIM)   /* 4194304 */
#define QSC    0.18033688f                       /* 64^-0.5 * log2(e), folded into q */

typedef unsigned short ushort_t;
typedef __attribute__((ext_vector_type(8))) short short8;
typedef __attribute__((ext_vector_type(4))) float f32x4;
typedef __attribute__((ext_vector_type(4))) unsigned short us4;

__device__ __forceinline__ ushort_t f2b(float f) {
  union { float f; unsigned int u; } cv; cv.f = f;
  unsigned int u = cv.u;
  unsigned int r = (u + 0x7fffu + ((u >> 16) & 1u)) >> 16;  // RNE
  return (ushort_t)r;
}

__device__ __forceinline__ float b2f(ushort_t b) {
  union { unsigned int u; float f; } cv; cv.u = ((unsigned int)b) << 16;
  return cv.f;
}

__device__ __forceinline__ float fexp2(float x) {
#if __has_builtin(__builtin_amdgcn_exp2f)
  return __builtin_amdgcn_exp2f(x);
#else
  return exp2f(x);
#endif
}

__device__ __forceinline__ void gl_lds16(const void* g, void* l) {
  __builtin_amdgcn_global_load_lds(
      (const __attribute__((address_space(1))) void*)g,
      (__attribute__((address_space(3))) void*)l, 16, 0, 0);
}

// ---- fused pre-pass: transpose x (B,C,N)->xt (B,N,C) bf16  +  w fp32->bf16 --
__global__ __launch_bounds__(256) void k_pre(const float* __restrict__ x,
                                             const float* __restrict__ w0,
                                             const float* __restrict__ w1,
                                             const float* __restrict__ w2,
                                             const float* __restrict__ w3,
                                             ushort_t* __restrict__ xt,
                                             ushort_t* __restrict__ o0,
                                             ushort_t* __restrict__ o1,
                                             ushort_t* __restrict__ o2,
                                             ushort_t* __restrict__ o3) {
  __shared__ float t[32][33];
  int bid = blockIdx.x;
  if (bid < 4096) {  // transpose path
    int b   = bid >> 11;
    int rem = bid & 2047;
    int n0  = (rem & 63) * 32;
    int c0  = (rem >> 6) * 32;
    int tx = threadIdx.x & 31, ty = threadIdx.x >> 5;  // (32,8)
#pragma unroll
    for (int l = 0; l < 4; l++)
      t[ty + l * 8][tx] = x[((size_t)(b * DIMC + c0 + ty + l * 8)) * NTOK + n0 + tx];
    __syncthreads();
#pragma unroll
    for (int l = 0; l < 4; l++)
      xt[((size_t)(b * NTOK + n0 + ty + l * 8)) * DIMC + c0 + tx] = f2b(t[tx][ty + l * 8]);
  } else {  // weight-convert path
    int cb = bid - 4096;
    const float* in; ushort_t* out; int base;
    if (cb < 3072)      { in = w0; out = o0; base = cb; }
    else if (cb < 4096) { in = w1; out = o1; base = cb - 3072; }
    else if (cb < 8192) { in = w2; out = o2; base = cb - 4096; }
    else                { in = w3; out = o3; base = cb - 8192; }
    int i = base * 256 + threadIdx.x;
    float4 v = ((const float4*)in)[i];
    us4 o; o.x = f2b(v.x); o.y = f2b(v.y); o.z = f2b(v.z); o.w = f2b(v.w);
    ((us4*)out)[i] = o;
  }
}

// ---------------- bf16 MFMA GEMM (128x128, 2-phase) --------------------------
// m97 structure: gl_lds staging, XOR source swizzle, double-buffer, one
// __syncthreads per 32-K step. Used for qkv/proj/fc2. 2-way split-K only.
template <int EPI, int NTX8, int KSTRIDE, int KLEN, int XROW>
__global__ __launch_bounds__(256) void k_gemm_bf16(const ushort_t* __restrict__ A,
                                                   const ushort_t* __restrict__ W,
                                                   const float* __restrict__ bias,
                                                   void* __restrict__ outv) {
  __shared__ ushort_t As[2][128 * 32];
  __shared__ ushort_t Bs[2][128 * 32];
  const int tid = threadIdx.x;
  const int lane = tid & 63, wv = tid >> 6;
  const int bid = blockIdx.x, kz = blockIdx.y;
  const int xcd = bid & 7, t = bid >> 3;
  const int row0 = XROW ? (xcd * NTX8 + (t % NTX8)) * 128 : (t / NTX8) * 128;
  const int col0 = XROW ? (t / NTX8) * 128 : (xcd * NTX8 + (t % NTX8)) * 128;
  const int wrow0 = (wv >> 1) * 64, wcol0 = (wv & 1) * 64;
  const int lm = lane & 15, lq = lane >> 4;
  const int srow = wv * 32 + (lane >> 2);
  const int gch = (lane & 3) ^ ((lane >> 3) & 3);
  const int sw8 = (lq ^ ((lm >> 1) & 3)) * 8;

  const ushort_t* Ab = A + (size_t)(row0 + srow) * KSTRIDE + (size_t)kz * KLEN + gch * 8;
  const ushort_t* Wb = W + (size_t)(col0 + srow) * KSTRIDE + (size_t)kz * KLEN + gch * 8;
  const size_t rstep = (size_t)16 * KSTRIDE;

  f32x4 acc[4][4];
#pragma unroll
  for (int i = 0; i < 4; i++)
#pragma unroll
    for (int j = 0; j < 4; j++) acc[i][j] = (f32x4){0.f, 0.f, 0.f, 0.f};

#define STAGE(buf, k0) do {                                      \
    gl_lds16(Ab + (k0),         &As[buf][wv * 1024]);            \
    gl_lds16(Ab + rstep + (k0), &As[buf][wv * 1024 + 512]);      \
    gl_lds16(Wb + (k0),         &Bs[buf][wv * 1024]);            \
    gl_lds16(Wb + rstep + (k0), &Bs[buf][wv * 1024 + 512]);      \
  } while (0)

  auto compute = [&](int buf) {
    short8 af[4], bf[4];
#pragma unroll
    for (int mi = 0; mi < 4; mi++)
      af[mi] = *(const short8*)&As[buf][(wrow0 + mi * 16 + lm) * 32 + sw8];
#pragma unroll
    for (int ni = 0; ni < 4; ni++)
      bf[ni] = *(const short8*)&Bs[buf][(wcol0 + ni * 16 + lm) * 32 + sw8];
#pragma unroll
    for (int mi = 0; mi < 4; mi++)
#pragma unroll
      for (int ni = 0; ni < 4; ni++)
        acc[mi][ni] = __builtin_amdgcn_mfma_f32_16x16x32_bf16(af[mi], bf[ni], acc[mi][ni], 0, 0, 0);
  };

  constexpr int S = KLEN / 32;
  STAGE(0, 0);
#pragma unroll 1
  for (int kk = 0; kk < S; kk++) {
    __syncthreads();
    if (kk + 1 < S) STAGE((kk + 1) & 1, (kk + 1) * 32);
    compute(kk & 1);
  }
#undef STAGE

#pragma unroll
  for (int mi = 0; mi < 4; mi++) {
#pragma unroll
    for (int ni = 0; ni < 4; ni++) {
#pragma unroll
      for (int r = 0; r < 4; r++) {
        const int row = row0 + wrow0 + mi * 16 + lq * 4 + r;
        const int col = col0 + wcol0 + ni * 16 + lm;
        float v = acc[mi][ni][r];
        if (EPI != 4) v += bias[col];
        if (EPI == 0) {  // qkv scatter
          int which = col >> 10, rem = col & 1023, hh = rem >> 6, d = rem & 63;
          int bb = row >> 11, n = row & 2047;
          size_t bh = (size_t)(bb * HEADS + hh);
          ushort_t* o16 = (ushort_t*)outv;
          if (which == 0)
            o16[(bh * NTOK + n) * HDIM + d] = f2b(v * QSC);
          else if (which == 1)
            o16[QSZ + (bh * NTOK + n) * HDIM + d] = f2b(v);
          else
            o16[2 * QSZ + (bh * HDIM + d) * NTOK + n] = f2b(v);
        } else {  // EPI==4: raw bf16 partial for split-K
          ((ushort_t*)outv)[(size_t)kz * MROWS * DIMC + (size_t)row * DIMC + col] = f2b(v);
        }
      }
    }
  }
}

// ---------------- fc1: 256x256 8-phase counted-vmcnt GEMM (T2+T3+T4+T5) ------
// M=N=4096, K=1024 (NT=16 x BK=64), 256 WGs (1/CU), 512 thr = 8 waves (2Mx4N).
// Per wave: 128x64 output = acc[8][4]. LDS 128KB: As/Bs[2][256x64].
// Schedule per K-tile (4 phases, quadrant MFMA x16):
//   q0: rd af[0-3],bf[0-1]; issue A-lo(k+1)   [other buffer - safe]
//   q1: rd bf[2-3];         issue A-hi(k+1)
//   q2: rd af[4-7];         issue B-lo(k+2)   [same buffer; B reads done @q1 barrier]
//   q3: (bf01 live);        issue B-hi(k+2)
// Tile boundary: vmcnt(4) leaves B(k+1)'s 4 loads in flight (issue-order trace:
// ...,A-lo(k),A-hi(k),B-lo(k+1),B-hi(k+1) -> newest-needed A-hi(k) is 5th-oldest
// => vmcnt(4) certifies tile k); vmcnt(0) at last tile (tail has no B(k+1)).
// Raw s_barrier (no drain); compiler fences stop ds_read hoisting; setprio(T5).
// XOR-chunk swizzle (8-chunk rows): staged gch=(c)^(row&7); read undoes it ->
// bank-uniform ds_read_b128 (8 words/bank = structural minimum).
__global__ __launch_bounds__(512, 2) void k_gemm256_fc1(const ushort_t* __restrict__ A,
                                                        const ushort_t* __restrict__ W,
                                                        const float* __restrict__ bias,
                                                        ushort_t* __restrict__ out) {
  __shared__ ushort_t As[2][256 * 64];
  __shared__ ushort_t Bs[2][256 * 64];
  const int tid = threadIdx.x;
  const int lane = tid & 63, wid = tid >> 6;
  const int wr = wid >> 2, wc = wid & 3;           // 2M x 4N waves
  const int lm = lane & 15, quad = lane >> 4;
  const int bid = blockIdx.x;
  const int lin = (bid & 7) * 32 + (bid >> 3);     // XCD-contiguous tile groups
  const int row0 = (lin >> 4) * 256, col0 = (lin & 15) * 256;
  const int swz = lm & 7;

  // staging: thread covers slot s=j*512+tid of a 128-row half (8x16B chunks/row)
  const int gch = (tid & 7) ^ ((tid >> 3) & 7);
  const ushort_t* Ab = A + (size_t)(row0 + (tid >> 3)) * 1024 + gch * 8;
  const ushort_t* Wb = W + (size_t)(col0 + (tid >> 3)) * 1024 + gch * 8;
  const int dbase = wid * 512;  // elements; HW adds lane*16B

  auto stA = [&](int buf, int half, int kt) {
    const ushort_t* s = Ab + (size_t)(half * 128) * 1024 + kt * 64;
    gl_lds16(s,             &As[buf][half * 8192 + dbase]);
    gl_lds16(s + 64 * 1024, &As[buf][half * 8192 + 4096 + dbase]);
  };
  auto stB = [&](int buf, int half, int kt) {
    const ushort_t* s = Wb + (size_t)(half * 128) * 1024 + kt * 64;
    gl_lds16(s,             &Bs[buf][half * 8192 + dbase]);
    gl_lds16(s + 64 * 1024, &Bs[buf][half * 8192 + 4096 + dbase]);
  };

  f32x4 acc[8][4];
#pragma unroll
  for (int i = 0; i < 8; i++)
#pragma unroll
    for (int j = 0; j < 4; j++) acc[i][j] = (f32x4){0.f, 0.f, 0.f, 0.f};

  short8 af[4][2], bf[4][2];

  auto rdAf = [&](int buf, int mih) {
#pragma unroll
    for (int mi = 0; mi < 4; mi++)
#pragma unroll
      for (int ks = 0; ks < 2; ks++)
        af[mi][ks] = *(const short8*)&As[buf][(wr * 128 + (mih * 4 + mi) * 16 + lm) * 64 +
                                             (((ks * 4 + quad) ^ swz) * 8)];
  };
  auto rdBf = [&](int buf, int nh) {
#pragma unroll
    for (int nn = 0; nn < 2; nn++)
#pragma unroll
      for (int ks = 0; ks < 2; ks++)
        bf[nh * 2 + nn][ks] = *(const short8*)&Bs[buf][(wc * 64 + (nh * 2 + nn) * 16 + lm) * 64 +
                                                       (((ks * 4 + quad) ^ swz) * 8)];
  };
  auto quadMM = [&](int m0, int n0) {
    __builtin_amdgcn_s_setprio(1);
#pragma unroll
    for (int mi = 0; mi < 4; mi++)
#pragma unroll
      for (int ni = 0; ni < 2; ni++)
#pragma unroll
        for (int ks = 0; ks < 2; ks++)
          acc[m0 + mi][n0 + ni] = __builtin_amdgcn_mfma_f32_16x16x32_bf16(
              af[mi][ks], bf[n0 + ni][ks], acc[m0 + mi][n0 + ni], 0, 0, 0);
    __builtin_amdgcn_s_setprio(0);
  };

  constexpr int NT = 16;  // K=1024 / BK=64
  // prologue: B(0), A(0), B(1) — order matches steady-state vmcnt counting
  stB(0, 0, 0); stB(0, 1, 0);
  stA(0, 0, 0); stA(0, 1, 0);
  stB(1, 0, 1); stB(1, 1, 1);

#pragma unroll 1
  for (int kt = 0; kt < NT; kt++) {
    const int buf = kt & 1;
    // tile boundary: certify tile kt landed; leave B(kt+1)'s 4 loads in flight
    if (kt + 1 < NT) __builtin_amdgcn_s_waitcnt(0x0F74);  // vmcnt(4), lgkm nowait
    else             __builtin_amdgcn_s_waitcnt(0x0F70);  // vmcnt(0)
    __builtin_amdgcn_s_barrier();
    asm volatile("" ::: "memory");

    // ---- phase 0: af[0-3], bf[0-1]; prefetch A-lo(kt+1)
    rdAf(buf, 0);
    rdBf(buf, 0);
    if (kt + 1 < NT) stA(buf ^ 1, 0, kt + 1);
    asm volatile("" ::: "memory");
    __builtin_amdgcn_s_barrier();
    quadMM(0, 0);                       // acc[0-3][0-1]
    __builtin_amdgcn_s_barrier();
    asm volatile("" ::: "memory");

    // ---- phase 1: bf[2-3]; prefetch A-hi(kt+1)
    rdBf(buf, 1);
    if (kt + 1 < NT) stA(buf ^ 1, 1, kt + 1);
    asm volatile("" ::: "memory");
    __builtin_amdgcn_s_barrier();
    quadMM(0, 2);                       // acc[0-3][2-3]
    __builtin_amdgcn_s_barrier();       // certifies ALL waves' B-reads done
    asm volatile("" ::: "memory");

    // ---- phase 2: af[4-7]; prefetch B-lo(kt+2) into SAME buf (B consumed)
    rdAf(buf, 1);
    if (kt + 2 < NT) stB(buf, 0, kt + 2);
    asm volatile("" ::: "memory");
    __builtin_amdgcn_s_barrier();
    quadMM(4, 2);                       // acc[4-7][2-3] (bf[2-3] live)
    __builtin_amdgcn_s_barrier();
    asm volatile("" ::: "memory");

    // ---- phase 3: no reads (bf[0-1] live since q0); prefetch B-hi(kt+2)
    if (kt + 2 < NT) stB(buf, 1, kt + 2);
    asm volatile("" ::: "memory");
    __builtin_amdgcn_s_barrier();
    quadMM(4, 0);                       // acc[4-7][0-1]
    // loop-top barrier doubles as phase-3 post-MFMA barrier
  }

  // epilogue: bias + bf16 store (raw; GELU applied in k_ln)
#pragma unroll
  for (int mi = 0; mi < 8; mi++)
#pragma unroll
    for (int ni = 0; ni < 4; ni++)
#pragma unroll
      for (int r = 0; r < 4; r++) {
        const int row = row0 + wr * 128 + mi * 16 + quad * 4 + r;
        const int col = col0 + wc * 64 + ni * 16 + lm;
        out[(size_t)row * HIDDEN + col] = f2b(acc[mi][ni][r] + bias[col]);
      }
}

// ---------------- combine proj partials: hb = bf16(2*(p0+p1+bias)) -----------
__global__ __launch_bounds__(256) void k_comb_proj(const ushort_t* __restrict__ p0,
                                                   const ushort_t* __restrict__ p1,
                                                   const float* __restrict__ bias,
                                                   ushort_t* __restrict__ hb) {
  int i = blockIdx.x * 256 + threadIdx.x;
  int colb = (i & 255) * 4;
  us4 a = ((const us4*)p0)[i];
  us4 b = ((const us4*)p1)[i];
  us4 o;
  o.x = f2b(2.f * (b2f(a.x) + b2f(b.x) + bias[colb + 0]));
  o.y = f2b(2.f * (b2f(a.y) + b2f(b.y) + bias[colb + 1]));
  o.z = f2b(2.f * (b2f(a.z) + b2f(b.z) + bias[colb + 2]));
  o.w = f2b(2.f * (b2f(a.w) + b2f(b.w) + bias[colb + 3]));
  ((us4*)hb)[i] = o;
}

// ------- combine fc2 partials + residual, transposed store to (B,C,N) --------
__global__ __launch_bounds__(256) void k_comb_fc2(const ushort_t* __restrict__ p0,
                                                  const ushort_t* __restrict__ p1,
                                                  const ushort_t* __restrict__ hb,
                                                  const float* __restrict__ bias,
                                                  float* __restrict__ out) {
  __shared__ float t[32][33];
  int b  = blockIdx.z;
  int c0 = blockIdx.y * 32, n0 = blockIdx.x * 32;
  int tx = threadIdx.x, ty = threadIdx.y;  // (32,8)
#pragma unroll
  for (int l = 0; l < 4; l++) {
    size_t idx = ((size_t)(b * NTOK + n0 + ty + l * 8)) * DIMC + c0 + tx;
    t[ty + l * 8][tx] = b2f(p0[idx]) + b2f(p1[idx]) + b2f(hb[idx]) + bias[c0 + tx];
  }
  __syncthreads();
#pragma unroll
  for (int l = 0; l < 4; l++)
    out[((size_t)(b * DIMC + c0 + ty + l * 8)) * NTOK + n0 + tx] = t[tx][ty + l * 8];
}

// ---------------- MFMA flash attention, fixed-max softmax_one ----------------
// (Round-0 structure — best measured 65.2us across 7 rounds; 4 structural
// alternatives all regressed or tied.)
__global__ __launch_bounds__(256) void k_attn_mfma(const ushort_t* __restrict__ qkv,
                                                   const int* __restrict__ mask,
                                                   ushort_t* __restrict__ scram) {
  __shared__ ushort_t Kl[2][64 * 64];
  __shared__ ushort_t Vl[2][64 * 64];
  __shared__ ushort_t Pl[4 * 32 * 72];
  const int tid = threadIdx.x;
  const int lane = tid & 63, w = tid >> 6;
  const int lm = lane & 15, quad = lane >> 4;
  const int bh = blockIdx.y, b = bh >> 4, h = bh & 15;
  const int q0 = blockIdx.x * 128 + w * 32;
  const ushort_t* qg  = qkv + (size_t)bh * NTOK * HDIM;
  const ushort_t* kg  = qkv + QSZ + (size_t)bh * NTOK * HDIM;
  const ushort_t* vTg = qkv + 2 * QSZ + (size_t)bh * HDIM * NTOK;
  ushort_t* Pw = &Pl[w * 32 * 72];

  const short8 ones = {0x3F80, 0x3F80, 0x3F80, 0x3F80, 0x3F80, 0x3F80, 0x3F80, 0x3F80};

  short8 qf[2][2];
#pragma unroll
  for (int qs = 0; qs < 2; qs++)
#pragma unroll
    for (int hf = 0; hf < 2; hf++)
      qf[qs][hf] = *(const short8*)&qg[(size_t)(q0 + qs * 16 + lm) * HDIM + hf * 32 + quad * 8];

  bool mk[2][4];
#pragma unroll
  for (int qs = 0; qs < 2; qs++)
#pragma unroll
    for (int r = 0; r < 4; r++)
      mk[qs][r] = mask[(size_t)bh * NTOK + q0 + qs * 16 + quad * 4 + r] != 0;

  f32x4 O[2][4], La[2];
#pragma unroll
  for (int qs = 0; qs < 2; qs++) {
    La[qs] = (f32x4){0.f, 0.f, 0.f, 0.f};
#pragma unroll
    for (int r = 0; r < 4; r++) O[qs][r] = (f32x4){0.f, 0.f, 0.f, 0.f};
  }

  const int s0 = tid, s1 = tid + 256;
  const int r0 = s0 >> 3, g0 = (s0 & 7) ^ (r0 & 7);
  const int r1 = s1 >> 3, g1 = (s1 & 7) ^ (r1 & 7);

  gl_lds16(kg + (size_t)r0 * HDIM + g0 * 8, &Kl[0][s0 * 8]);
  gl_lds16(kg + (size_t)r1 * HDIM + g1 * 8, &Kl[0][s1 * 8]);
  gl_lds16(vTg + (size_t)r0 * NTOK + g0 * 8, &Vl[0][s0 * 8]);
  gl_lds16(vTg + (size_t)r1 * NTOK + g1 * 8, &Vl[0][s1 * 8]);

  for (int kt = 0; kt < NTOK; kt += 64) {
    const int cur = (kt >> 6) & 1, nxt = cur ^ 1;
    __syncthreads();
    if (kt + 64 < NTOK) {
      gl_lds16(kg + (size_t)(kt + 64 + r0) * HDIM + g0 * 8, &Kl[nxt][s0 * 8]);
      gl_lds16(kg + (size_t)(kt + 64 + r1) * HDIM + g1 * 8, &Kl[nxt][s1 * 8]);
      gl_lds16(vTg + (size_t)r0 * NTOK + kt + 64 + g0 * 8, &Vl[nxt][s0 * 8]);
      gl_lds16(vTg + (size_t)r1 * NTOK + kt + 64 + g1 * 8, &Vl[nxt][s1 * 8]);
    }

    short8 kf[4][2];
#pragma unroll
    for (int ksub = 0; ksub < 4; ksub++)
#pragma unroll
      for (int hf = 0; hf < 2; hf++)
        kf[ksub][hf] = *(const short8*)&Kl[cur][(ksub * 16 + lm) * 64 + ((4 * hf + quad) ^ (lm & 7)) * 8];

#pragma unroll
    for (int qs = 0; qs < 2; qs++) {
      f32x4 S[4];
#pragma unroll
      for (int ksub = 0; ksub < 4; ksub++) {
        S[ksub] = (f32x4){0.f, 0.f, 0.f, 0.f};
        S[ksub] = __builtin_amdgcn_mfma_f32_16x16x32_bf16(qf[qs][0], kf[ksub][0], S[ksub], 0, 0, 0);
        S[ksub] = __builtin_amdgcn_mfma_f32_16x16x32_bf16(qf[qs][1], kf[ksub][1], S[ksub], 0, 0, 0);
      }
#pragma unroll
      for (int r = 0; r < 4; r++) {
        const int prow = qs * 16 + quad * 4 + r;
#pragma unroll
        for (int ksub = 0; ksub < 4; ksub++) {
          float p = mk[qs][r] ? fexp2(S[ksub][r]) : 1.0f;
          Pw[prow * 72 + ksub * 16 + lm] = (ushort_t)(__float_as_uint(p) >> 16);
        }
      }
    }
    __builtin_amdgcn_s_waitcnt(0xC07F);

    short8 vf[4][2];
#pragma unroll
    for (int dsub = 0; dsub < 4; dsub++)
#pragma unroll
      for (int hf = 0; hf < 2; hf++)
        vf[dsub][hf] = *(const short8*)&Vl[cur][(dsub * 16 + lm) * 64 + ((4 * hf + quad) ^ (lm & 7)) * 8];

#pragma unroll
    for (int qs = 0; qs < 2; qs++) {
      short8 pf[2];
#pragma unroll
      for (int hf = 0; hf < 2; hf++)
        pf[hf] = *(const short8*)&Pw[(qs * 16 + lm) * 72 + hf * 32 + quad * 8];
#pragma unroll
      for (int dsub = 0; dsub < 4; dsub++) {
        O[qs][dsub] = __builtin_amdgcn_mfma_f32_16x16x32_bf16(pf[0], vf[dsub][0], O[qs][dsub], 0, 0, 0);
        O[qs][dsub] = __builtin_amdgcn_mfma_f32_16x16x32_bf16(pf[1], vf[dsub][1], O[qs][dsub], 0, 0, 0);
      }
      La[qs] = __builtin_amdgcn_mfma_f32_16x16x32_bf16(pf[0], ones, La[qs], 0, 0, 0);
      La[qs] = __builtin_amdgcn_mfma_f32_16x16x32_bf16(pf[1], ones, La[qs], 0, 0, 0);
    }
  }

#pragma unroll
  for (int qs = 0; qs < 2; qs++)
#pragma unroll
    for (int r = 0; r < 4; r++) {
      int n = q0 + qs * 16 + quad * 4 + r;
      float inv = 1.f / (1.f + La[qs][r]);
      int n1 = n >> 10, nn0 = n & 1023;
#pragma unroll
      for (int dsub = 0; dsub < 4; dsub++) {
        int d = dsub * 16 + lm;
        int np = d * 32 + h * 2 + n1;
        scram[((size_t)(b * NTOK + np)) * DIMC + nn0] = f2b(O[qs][dsub][r] * inv);
      }
    }
}

// ---------------- GELU (exact, erf) + row LayerNorm over HIDDEN=4096 ---------
__global__ __launch_bounds__(256) void k_ln(ushort_t* __restrict__ mid,
                                            const float* __restrict__ g,
                                            const float* __restrict__ bta) {
  const int row = blockIdx.x;
  ushort_t* p = mid + (size_t)row * HIDDEN;
  const int tid = threadIdx.x;
  float lv[16];
  float s = 0.f, s2 = 0.f;
#pragma unroll
  for (int i = 0; i < 4; i++) {
    us4 u = *(const us4*)&p[tid * 4 + i * 1024];
#pragma unroll
    for (int j = 0; j < 4; j++) {
      float xx = b2f((j == 0) ? u.x : (j == 1) ? u.y : (j == 2) ? u.z : u.w);
      xx = 0.5f * xx * (1.f + erff(xx * 0.70710678118654752f));  // exact GELU
      lv[i * 4 + j] = xx;
      s += xx;
      s2 += xx * xx;
    }
  }
#pragma unroll
  for (int off = 32; off > 0; off >>= 1) {
    s += __shfl_down(s, off);
    s2 += __shfl_down(s2, off);
  }
  __shared__ float rs[4], rs2[4];
  if ((tid & 63) == 0) { rs[tid >> 6] = s; rs2[tid >> 6] = s2; }
  __syncthreads();
  float ts = rs[0] + rs[1] + rs[2] + rs[3];
  float ts2 = rs2[0] + rs2[1] + rs2[2] + rs2[3];
  float mu = ts * (1.f / HIDDEN);
  float var = ts2 * (1.f / HIDDEN) - mu * mu;
  float rstd = rsqrtf(var + 1e-5f);
#pragma unroll
  for (int i = 0; i < 4; i++) {
    us4 o;
#pragma unroll
    for (int j = 0; j < 4; j++) {
      int f = tid * 4 + i * 1024 + j;
      float y = (lv[i * 4 + j] - mu) * rstd * g[f] + bta[f];
      ushort_t ob = f2b(y);
      if (j == 0) o.x = ob; else if (j == 1) o.y = ob; else if (j == 2) o.z = ob; else o.w = ob;
    }
    *(us4*)&p[tid * 4 + i * 1024] = o;
  }
}

extern "C" void kernel_launch(void* const* d_in, const int* in_sizes, int n_in,
                              void* d_out, int out_size, void* d_ws, size_t ws_size,
                              hipStream_t stream) {
  const float* x      = (const float*)d_in[0];
  const int*   mask   = (const int*)d_in[1];
  const float* qkv_w  = (const float*)d_in[2];
  const float* qkv_b  = (const float*)d_in[3];
  const float* proj_w = (const float*)d_in[4];
  const float* proj_b = (const float*)d_in[5];
  const float* fc1_w  = (const float*)d_in[6];
  const float* fc1_b  = (const float*)d_in[7];
  const float* ln_g   = (const float*)d_in[8];
  const float* ln_b   = (const float*)d_in[9];
  const float* fc2_w  = (const float*)d_in[10];
  const float* fc2_b  = (const float*)d_in[11];

  char* w = (char*)d_ws;
  ushort_t* qkv16  = (ushort_t*)w;           w += 3 * QSZ * 2;                    // 25.2 MB
  ushort_t* xtb    = (ushort_t*)w;           w += (size_t)MROWS * DIMC * 2;       //  8.4 MB
  ushort_t* scramb = (ushort_t*)w;           w += (size_t)MROWS * DIMC * 2;       //  8.4 MB
  ushort_t* hb     = (ushort_t*)w;           w += (size_t)MROWS * DIMC * 2;       //  8.4 MB
  ushort_t* mid    = (ushort_t*)w;           w += (size_t)MROWS * HIDDEN * 2;     // 33.6 MB
  ushort_t* wqkvb  = (ushort_t*)w;           w += (size_t)3 * DIMC * DIMC * 2;    //  6.3 MB
  ushort_t* wprojb = (ushort_t*)w;           w += (size_t)DIMC * DIMC * 2;        //  2.1 MB
  ushort_t* wfc1b  = (ushort_t*)w;           w += (size_t)HIDDEN * DIMC * 2;      //  8.4 MB
  ushort_t* wfc2b  = (ushort_t*)w;           w += (size_t)DIMC * HIDDEN * 2;      //  8.4 MB
  ushort_t* pbuf   = (ushort_t*)w;           w += (size_t)2 * MROWS * DIMC * 2;   // 16.8 MB (bf16 partials)
  ushort_t* pbuf1  = pbuf + (size_t)MROWS * DIMC;

  k_pre<<<dim3(4096 + 12288), 256, 0, stream>>>(x, qkv_w, proj_w, fc1_w, fc2_w,
                                                xtb, wqkvb, wprojb, wfc1b, wfc2b);

  // qkv: XROW (A-panel per XCD L2-resident)
  k_gemm_bf16<0, 4, DIMC, DIMC, 1><<<dim3(24 * 32), 256, 0, stream>>>(
      xtb, wqkvb, qkv_b, qkv16);
  k_attn_mfma<<<dim3(NTOK / 128, BATCH * HEADS), 256, 0, stream>>>(
      qkv16, mask, scramb);
  // proj: split-K=2, bf16 partials; XROW
  k_gemm_bf16<4, 4, DIMC, 512, 1><<<dim3(8 * 32, 2), 256, 0, stream>>>(
      scramb, wprojb, nullptr, pbuf);
  k_comb_proj<<<dim3(4096), 256, 0, stream>>>(pbuf, pbuf1, proj_b, hb);
  // fc1: 256x256 8-phase counted-vmcnt kernel (256 WGs, 512 thr)
  k_gemm256_fc1<<<dim3(256), 512, 0, stream>>>(hb, wfc1b, fc1_b, mid);
  k_ln<<<dim3(MROWS), 256, 0, stream>>>(mid, ln_g, ln_b);
  // fc2: split-K=2; XROW
  k_gemm_bf16<4, 4, HIDDEN, 2048, 1><<<dim3(8 * 32, 2), 256, 0, stream>>>(
      mid, wfc2b, nullptr, pbuf);
  k_comb_fc2<<<dim3(NTOK / 32, DIMC / 32, BATCH), dim3(32, 8), 0, stream>>>(
      pbuf, pbuf1, hb, fc2_b, (float*)d_out);
}

// Round 12
// 336.685 us; speedup vs baseline: 1.1634x; 1.0230x over previous
//
#include <hip/hip_runtime.h>
#include <math.h>

#define DIMC   1024
#define NTOK   2048
#define BATCH  2
#define HEADS  16
#define HDIM   64
#define HIDDEN 4096
#define MROWS  (BATCH*NTOK)                      /* 4096 token-rows */
#define QSZ    ((size_t)BATCH*HEADS*NTOK*HDIM)   /* 4194304 */
#define QSC    0.18033688f                       /* 64^-0.5 * log2(e), folded into q */

typedef unsigned short ushort_t;
typedef __attribute__((ext_vector_type(8))) short short8;
typedef __attribute__((ext_vector_type(4))) float f32x4;
typedef __attribute__((ext_vector_type(4))) unsigned short us4;

__device__ __forceinline__ ushort_t f2b(float f) {
  union { float f; unsigned int u; } cv; cv.f = f;
  unsigned int u = cv.u;
  unsigned int r = (u + 0x7fffu + ((u >> 16) & 1u)) >> 16;  // RNE
  return (ushort_t)r;
}

__device__ __forceinline__ float b2f(ushort_t b) {
  union { unsigned int u; float f; } cv; cv.u = ((unsigned int)b) << 16;
  return cv.f;
}

__device__ __forceinline__ float fexp2(float x) {
#if __has_builtin(__builtin_amdgcn_exp2f)
  return __builtin_amdgcn_exp2f(x);
#else
  return exp2f(x);
#endif
}

__device__ __forceinline__ void gl_lds16(const void* g, void* l) {
  __builtin_amdgcn_global_load_lds(
      (const __attribute__((address_space(1))) void*)g,
      (__attribute__((address_space(3))) void*)l, 16, 0, 0);
}

// ---- fused pre-pass: transpose x (B,C,N)->xt (B,N,C) bf16  +  w fp32->bf16 --
__global__ __launch_bounds__(256) void k_pre(const float* __restrict__ x,
                                             const float* __restrict__ w0,
                                             const float* __restrict__ w1,
                                             const float* __restrict__ w2,
                                             const float* __restrict__ w3,
                                             ushort_t* __restrict__ xt,
                                             ushort_t* __restrict__ o0,
                                             ushort_t* __restrict__ o1,
                                             ushort_t* __restrict__ o2,
                                             ushort_t* __restrict__ o3) {
  __shared__ float t[32][33];
  int bid = blockIdx.x;
  if (bid < 4096) {  // transpose path
    int b   = bid >> 11;
    int rem = bid & 2047;
    int n0  = (rem & 63) * 32;
    int c0  = (rem >> 6) * 32;
    int tx = threadIdx.x & 31, ty = threadIdx.x >> 5;  // (32,8)
#pragma unroll
    for (int l = 0; l < 4; l++)
      t[ty + l * 8][tx] = x[((size_t)(b * DIMC + c0 + ty + l * 8)) * NTOK + n0 + tx];
    __syncthreads();
#pragma unroll
    for (int l = 0; l < 4; l++)
      xt[((size_t)(b * NTOK + n0 + ty + l * 8)) * DIMC + c0 + tx] = f2b(t[tx][ty + l * 8]);
  } else {  // weight-convert path
    int cb = bid - 4096;
    const float* in; ushort_t* out; int base;
    if (cb < 3072)      { in = w0; out = o0; base = cb; }
    else if (cb < 4096) { in = w1; out = o1; base = cb - 3072; }
    else if (cb < 8192) { in = w2; out = o2; base = cb - 4096; }
    else                { in = w3; out = o3; base = cb - 8192; }
    int i = base * 256 + threadIdx.x;
    float4 v = ((const float4*)in)[i];
    us4 o; o.x = f2b(v.x); o.y = f2b(v.y); o.z = f2b(v.z); o.w = f2b(v.w);
    ((us4*)out)[i] = o;
  }
}

// ---------------- bf16 MFMA GEMM (128x128, 2-phase) --------------------------
// m97 structure. Used for qkv (192-WG 256-tile would under-fill CUs) and proj
// (K too short for the 8-phase NT=16 loop). 2-way split-K only.
template <int EPI, int NTX8, int KSTRIDE, int KLEN, int XROW>
__global__ __launch_bounds__(256) void k_gemm_bf16(const ushort_t* __restrict__ A,
                                                   const ushort_t* __restrict__ W,
                                                   const float* __restrict__ bias,
                                                   void* __restrict__ outv) {
  __shared__ ushort_t As[2][128 * 32];
  __shared__ ushort_t Bs[2][128 * 32];
  const int tid = threadIdx.x;
  const int lane = tid & 63, wv = tid >> 6;
  const int bid = blockIdx.x, kz = blockIdx.y;
  const int xcd = bid & 7, t = bid >> 3;
  const int row0 = XROW ? (xcd * NTX8 + (t % NTX8)) * 128 : (t / NTX8) * 128;
  const int col0 = XROW ? (t / NTX8) * 128 : (xcd * NTX8 + (t % NTX8)) * 128;
  const int wrow0 = (wv >> 1) * 64, wcol0 = (wv & 1) * 64;
  const int lm = lane & 15, lq = lane >> 4;
  const int srow = wv * 32 + (lane >> 2);
  const int gch = (lane & 3) ^ ((lane >> 3) & 3);
  const int sw8 = (lq ^ ((lm >> 1) & 3)) * 8;

  const ushort_t* Ab = A + (size_t)(row0 + srow) * KSTRIDE + (size_t)kz * KLEN + gch * 8;
  const ushort_t* Wb = W + (size_t)(col0 + srow) * KSTRIDE + (size_t)kz * KLEN + gch * 8;
  const size_t rstep = (size_t)16 * KSTRIDE;

  f32x4 acc[4][4];
#pragma unroll
  for (int i = 0; i < 4; i++)
#pragma unroll
    for (int j = 0; j < 4; j++) acc[i][j] = (f32x4){0.f, 0.f, 0.f, 0.f};

#define STAGE(buf, k0) do {                                      \
    gl_lds16(Ab + (k0),         &As[buf][wv * 1024]);            \
    gl_lds16(Ab + rstep + (k0), &As[buf][wv * 1024 + 512]);      \
    gl_lds16(Wb + (k0),         &Bs[buf][wv * 1024]);            \
    gl_lds16(Wb + rstep + (k0), &Bs[buf][wv * 1024 + 512]);      \
  } while (0)

  auto compute = [&](int buf) {
    short8 af[4], bf[4];
#pragma unroll
    for (int mi = 0; mi < 4; mi++)
      af[mi] = *(const short8*)&As[buf][(wrow0 + mi * 16 + lm) * 32 + sw8];
#pragma unroll
    for (int ni = 0; ni < 4; ni++)
      bf[ni] = *(const short8*)&Bs[buf][(wcol0 + ni * 16 + lm) * 32 + sw8];
#pragma unroll
    for (int mi = 0; mi < 4; mi++)
#pragma unroll
      for (int ni = 0; ni < 4; ni++)
        acc[mi][ni] = __builtin_amdgcn_mfma_f32_16x16x32_bf16(af[mi], bf[ni], acc[mi][ni], 0, 0, 0);
  };

  constexpr int S = KLEN / 32;
  STAGE(0, 0);
#pragma unroll 1
  for (int kk = 0; kk < S; kk++) {
    __syncthreads();
    if (kk + 1 < S) STAGE((kk + 1) & 1, (kk + 1) * 32);
    compute(kk & 1);
  }
#undef STAGE

#pragma unroll
  for (int mi = 0; mi < 4; mi++) {
#pragma unroll
    for (int ni = 0; ni < 4; ni++) {
#pragma unroll
      for (int r = 0; r < 4; r++) {
        const int row = row0 + wrow0 + mi * 16 + lq * 4 + r;
        const int col = col0 + wcol0 + ni * 16 + lm;
        float v = acc[mi][ni][r];
        if (EPI != 4) v += bias[col];
        if (EPI == 0) {  // qkv scatter
          int which = col >> 10, rem = col & 1023, hh = rem >> 6, d = rem & 63;
          int bb = row >> 11, n = row & 2047;
          size_t bh = (size_t)(bb * HEADS + hh);
          ushort_t* o16 = (ushort_t*)outv;
          if (which == 0)
            o16[(bh * NTOK + n) * HDIM + d] = f2b(v * QSC);
          else if (which == 1)
            o16[QSZ + (bh * NTOK + n) * HDIM + d] = f2b(v);
          else
            o16[2 * QSZ + (bh * HDIM + d) * NTOK + n] = f2b(v);
        } else {  // EPI==4: raw bf16 partial for split-K
          ((ushort_t*)outv)[(size_t)kz * MROWS * DIMC + (size_t)row * DIMC + col] = f2b(v);
        }
      }
    }
  }
}

// ---------------- 256x256 8-phase counted-vmcnt GEMM (T2+T3+T4+T5) -----------
// Verified on fc1 (round 11: passed, ~1.5x vs 2-phase). 512 thr = 8 waves
// (2Mx4N), per wave 128x64 out = acc[8][4]. LDS 128KB. NT=16 K-tiles of 64
// (KLEN=1024 per kz slice). Schedule per K-tile (4 phases, quadrant MFMA):
//   q0: rd af[0-3],bf[0-1]; issue A-lo(k+1) [other buf]
//   q1: rd bf[2-3];         issue A-hi(k+1)
//   q2: rd af[4-7];         issue B-lo(k+2) [same buf; B reads done @q1 barrier]
//   q3: (bf01 live);        issue B-hi(k+2)
// Boundary: vmcnt(4) leaves B(k+1)'s 4 loads in flight; vmcnt(0) at last tile.
// Raw s_barrier; compiler fences; setprio around MFMA (T5).
// EPI: 2 = raw bf16 +bias, stride HIDDEN (fc1); 4 = bf16 partial at
//      outv + kz*MROWS*DIMC, stride DIMC, no bias (fc2 split-K).
// NCT = N/256 col-tiles; NB8 = gridDim.x/8 (XCD-contiguous chunk size).
template <int EPI, int KSTRIDE, int NCT, int NB8>
__global__ __launch_bounds__(512, 2) void k_gemm256(const ushort_t* __restrict__ A,
                                                    const ushort_t* __restrict__ W,
                                                    const float* __restrict__ bias,
                                                    void* __restrict__ outv) {
  __shared__ ushort_t As[2][256 * 64];
  __shared__ ushort_t Bs[2][256 * 64];
  const int tid = threadIdx.x;
  const int lane = tid & 63, wid = tid >> 6;
  const int wr = wid >> 2, wc = wid & 3;           // 2M x 4N waves
  const int lm = lane & 15, quad = lane >> 4;
  const int bid = blockIdx.x, kz = blockIdx.y;
  const int lin = (bid & 7) * NB8 + (bid >> 3);    // XCD-contiguous tile groups
  const int row0 = (lin / NCT) * 256, col0 = (lin % NCT) * 256;
  const int swz = lm & 7;

  const int gch = (tid & 7) ^ ((tid >> 3) & 7);
  const ushort_t* Ab = A + (size_t)(row0 + (tid >> 3)) * KSTRIDE + (size_t)kz * 1024 + gch * 8;
  const ushort_t* Wb = W + (size_t)(col0 + (tid >> 3)) * KSTRIDE + (size_t)kz * 1024 + gch * 8;
  const int dbase = wid * 512;  // elements; HW adds lane*16B

  auto stA = [&](int buf, int half, int kt) {
    const ushort_t* s = Ab + (size_t)(half * 128) * KSTRIDE + kt * 64;
    gl_lds16(s,                &As[buf][half * 8192 + dbase]);
    gl_lds16(s + 64 * KSTRIDE, &As[buf][half * 8192 + 4096 + dbase]);
  };
  auto stB = [&](int buf, int half, int kt) {
    const ushort_t* s = Wb + (size_t)(half * 128) * KSTRIDE + kt * 64;
    gl_lds16(s,                &Bs[buf][half * 8192 + dbase]);
    gl_lds16(s + 64 * KSTRIDE, &Bs[buf][half * 8192 + 4096 + dbase]);
  };

  f32x4 acc[8][4];
#pragma unroll
  for (int i = 0; i < 8; i++)
#pragma unroll
    for (int j = 0; j < 4; j++) acc[i][j] = (f32x4){0.f, 0.f, 0.f, 0.f};

  short8 af[4][2], bf[4][2];

  auto rdAf = [&](int buf, int mih) {
#pragma unroll
    for (int mi = 0; mi < 4; mi++)
#pragma unroll
      for (int ks = 0; ks < 2; ks++)
        af[mi][ks] = *(const short8*)&As[buf][(wr * 128 + (mih * 4 + mi) * 16 + lm) * 64 +
                                             (((ks * 4 + quad) ^ swz) * 8)];
  };
  auto rdBf = [&](int buf, int nh) {
#pragma unroll
    for (int nn = 0; nn < 2; nn++)
#pragma unroll
      for (int ks = 0; ks < 2; ks++)
        bf[nh * 2 + nn][ks] = *(const short8*)&Bs[buf][(wc * 64 + (nh * 2 + nn) * 16 + lm) * 64 +
                                                       (((ks * 4 + quad) ^ swz) * 8)];
  };
  auto quadMM = [&](int m0, int n0) {
    __builtin_amdgcn_s_setprio(1);
#pragma unroll
    for (int mi = 0; mi < 4; mi++)
#pragma unroll
      for (int ni = 0; ni < 2; ni++)
#pragma unroll
        for (int ks = 0; ks < 2; ks++)
          acc[m0 + mi][n0 + ni] = __builtin_amdgcn_mfma_f32_16x16x32_bf16(
              af[mi][ks], bf[n0 + ni][ks], acc[m0 + mi][n0 + ni], 0, 0, 0);
    __builtin_amdgcn_s_setprio(0);
  };

  constexpr int NT = 16;  // KLEN=1024 / BK=64
  stB(0, 0, 0); stB(0, 1, 0);
  stA(0, 0, 0); stA(0, 1, 0);
  stB(1, 0, 1); stB(1, 1, 1);

#pragma unroll 1
  for (int kt = 0; kt < NT; kt++) {
    const int buf = kt & 1;
    if (kt + 1 < NT) __builtin_amdgcn_s_waitcnt(0x0F74);  // vmcnt(4)
    else             __builtin_amdgcn_s_waitcnt(0x0F70);  // vmcnt(0)
    __builtin_amdgcn_s_barrier();
    asm volatile("" ::: "memory");

    rdAf(buf, 0);
    rdBf(buf, 0);
    if (kt + 1 < NT) stA(buf ^ 1, 0, kt + 1);
    asm volatile("" ::: "memory");
    __builtin_amdgcn_s_barrier();
    quadMM(0, 0);
    __builtin_amdgcn_s_barrier();
    asm volatile("" ::: "memory");

    rdBf(buf, 1);
    if (kt + 1 < NT) stA(buf ^ 1, 1, kt + 1);
    asm volatile("" ::: "memory");
    __builtin_amdgcn_s_barrier();
    quadMM(0, 2);
    __builtin_amdgcn_s_barrier();
    asm volatile("" ::: "memory");

    rdAf(buf, 1);
    if (kt + 2 < NT) stB(buf, 0, kt + 2);
    asm volatile("" ::: "memory");
    __builtin_amdgcn_s_barrier();
    quadMM(4, 2);
    __builtin_amdgcn_s_barrier();
    asm volatile("" ::: "memory");

    if (kt + 2 < NT) stB(buf, 1, kt + 2);
    asm volatile("" ::: "memory");
    __builtin_amdgcn_s_barrier();
    quadMM(4, 0);
  }

#pragma unroll
  for (int mi = 0; mi < 8; mi++)
#pragma unroll
    for (int ni = 0; ni < 4; ni++)
#pragma unroll
      for (int r = 0; r < 4; r++) {
        const int row = row0 + wr * 128 + mi * 16 + quad * 4 + r;
        const int col = col0 + wc * 64 + ni * 16 + lm;
        if (EPI == 2) {
          ((ushort_t*)outv)[(size_t)row * HIDDEN + col] = f2b(acc[mi][ni][r] + bias[col]);
        } else {  // EPI==4: bf16 partial, stride DIMC
          ((ushort_t*)outv)[(size_t)kz * MROWS * DIMC + (size_t)row * DIMC + col] = f2b(acc[mi][ni][r]);
        }
      }
}

// ---------------- combine proj partials: hb = bf16(2*(p0+p1+bias)) -----------
__global__ __launch_bounds__(256) void k_comb_proj(const ushort_t* __restrict__ p0,
                                                   const ushort_t* __restrict__ p1,
                                                   const float* __restrict__ bias,
                                                   ushort_t* __restrict__ hb) {
  int i = blockIdx.x * 256 + threadIdx.x;
  int colb = (i & 255) * 4;
  us4 a = ((const us4*)p0)[i];
  us4 b = ((const us4*)p1)[i];
  us4 o;
  o.x = f2b(2.f * (b2f(a.x) + b2f(b.x) + bias[colb + 0]));
  o.y = f2b(2.f * (b2f(a.y) + b2f(b.y) + bias[colb + 1]));
  o.z = f2b(2.f * (b2f(a.z) + b2f(b.z) + bias[colb + 2]));
  o.w = f2b(2.f * (b2f(a.w) + b2f(b.w) + bias[colb + 3]));
  ((us4*)hb)[i] = o;
}

// --- combine fc2 partials (4-way) + residual, transposed store to (B,C,N) ----
__global__ __launch_bounds__(256) void k_comb_fc2(const ushort_t* __restrict__ p,
                                                  const ushort_t* __restrict__ hb,
                                                  const float* __restrict__ bias,
                                                  float* __restrict__ out) {
  __shared__ float t[32][33];
  const size_t SL = (size_t)MROWS * DIMC;
  int b  = blockIdx.z;
  int c0 = blockIdx.y * 32, n0 = blockIdx.x * 32;
  int tx = threadIdx.x, ty = threadIdx.y;  // (32,8)
#pragma unroll
  for (int l = 0; l < 4; l++) {
    size_t idx = ((size_t)(b * NTOK + n0 + ty + l * 8)) * DIMC + c0 + tx;
    t[ty + l * 8][tx] = b2f(p[idx]) + b2f(p[idx + SL]) + b2f(p[idx + 2 * SL]) +
                        b2f(p[idx + 3 * SL]) + b2f(hb[idx]) + bias[c0 + tx];
  }
  __syncthreads();
#pragma unroll
  for (int l = 0; l < 4; l++)
    out[((size_t)(b * DIMC + c0 + ty + l * 8)) * NTOK + n0 + tx] = t[tx][ty + l * 8];
}

// ---------------- MFMA flash attention, fixed-max softmax_one ----------------
// (Round-0 structure — best measured across 8 rounds; alternatives regressed.)
__global__ __launch_bounds__(256) void k_attn_mfma(const ushort_t* __restrict__ qkv,
                                                   const int* __restrict__ mask,
                                                   ushort_t* __restrict__ scram) {
  __shared__ ushort_t Kl[2][64 * 64];
  __shared__ ushort_t Vl[2][64 * 64];
  __shared__ ushort_t Pl[4 * 32 * 72];
  const int tid = threadIdx.x;
  const int lane = tid & 63, w = tid >> 6;
  const int lm = lane & 15, quad = lane >> 4;
  const int bh = blockIdx.y, b = bh >> 4, h = bh & 15;
  const int q0 = blockIdx.x * 128 + w * 32;
  const ushort_t* qg  = qkv + (size_t)bh * NTOK * HDIM;
  const ushort_t* kg  = qkv + QSZ + (size_t)bh * NTOK * HDIM;
  const ushort_t* vTg = qkv + 2 * QSZ + (size_t)bh * HDIM * NTOK;
  ushort_t* Pw = &Pl[w * 32 * 72];

  const short8 ones = {0x3F80, 0x3F80, 0x3F80, 0x3F80, 0x3F80, 0x3F80, 0x3F80, 0x3F80};

  short8 qf[2][2];
#pragma unroll
  for (int qs = 0; qs < 2; qs++)
#pragma unroll
    for (int hf = 0; hf < 2; hf++)
      qf[qs][hf] = *(const short8*)&qg[(size_t)(q0 + qs * 16 + lm) * HDIM + hf * 32 + quad * 8];

  bool mk[2][4];
#pragma unroll
  for (int qs = 0; qs < 2; qs++)
#pragma unroll
    for (int r = 0; r < 4; r++)
      mk[qs][r] = mask[(size_t)bh * NTOK + q0 + qs * 16 + quad * 4 + r] != 0;

  f32x4 O[2][4], La[2];
#pragma unroll
  for (int qs = 0; qs < 2; qs++) {
    La[qs] = (f32x4){0.f, 0.f, 0.f, 0.f};
#pragma unroll
    for (int r = 0; r < 4; r++) O[qs][r] = (f32x4){0.f, 0.f, 0.f, 0.f};
  }

  const int s0 = tid, s1 = tid + 256;
  const int r0 = s0 >> 3, g0 = (s0 & 7) ^ (r0 & 7);
  const int r1 = s1 >> 3, g1 = (s1 & 7) ^ (r1 & 7);

  gl_lds16(kg + (size_t)r0 * HDIM + g0 * 8, &Kl[0][s0 * 8]);
  gl_lds16(kg + (size_t)r1 * HDIM + g1 * 8, &Kl[0][s1 * 8]);
  gl_lds16(vTg + (size_t)r0 * NTOK + g0 * 8, &Vl[0][s0 * 8]);
  gl_lds16(vTg + (size_t)r1 * NTOK + g1 * 8, &Vl[0][s1 * 8]);

  for (int kt = 0; kt < NTOK; kt += 64) {
    const int cur = (kt >> 6) & 1, nxt = cur ^ 1;
    __syncthreads();
    if (kt + 64 < NTOK) {
      gl_lds16(kg + (size_t)(kt + 64 + r0) * HDIM + g0 * 8, &Kl[nxt][s0 * 8]);
      gl_lds16(kg + (size_t)(kt + 64 + r1) * HDIM + g1 * 8, &Kl[nxt][s1 * 8]);
      gl_lds16(vTg + (size_t)r0 * NTOK + kt + 64 + g0 * 8, &Vl[nxt][s0 * 8]);
      gl_lds16(vTg + (size_t)r1 * NTOK + kt + 64 + g1 * 8, &Vl[nxt][s1 * 8]);
    }

    short8 kf[4][2];
#pragma unroll
    for (int ksub = 0; ksub < 4; ksub++)
#pragma unroll
      for (int hf = 0; hf < 2; hf++)
        kf[ksub][hf] = *(const short8*)&Kl[cur][(ksub * 16 + lm) * 64 + ((4 * hf + quad) ^ (lm & 7)) * 8];

#pragma unroll
    for (int qs = 0; qs < 2; qs++) {
      f32x4 S[4];
#pragma unroll
      for (int ksub = 0; ksub < 4; ksub++) {
        S[ksub] = (f32x4){0.f, 0.f, 0.f, 0.f};
        S[ksub] = __builtin_amdgcn_mfma_f32_16x16x32_bf16(qf[qs][0], kf[ksub][0], S[ksub], 0, 0, 0);
        S[ksub] = __builtin_amdgcn_mfma_f32_16x16x32_bf16(qf[qs][1], kf[ksub][1], S[ksub], 0, 0, 0);
      }
#pragma unroll
      for (int r = 0; r < 4; r++) {
        const int prow = qs * 16 + quad * 4 + r;
#pragma unroll
        for (int ksub = 0; ksub < 4; ksub++) {
          float p = mk[qs][r] ? fexp2(S[ksub][r]) : 1.0f;
          Pw[prow * 72 + ksub * 16 + lm] = (ushort_t)(__float_as_uint(p) >> 16);
        }
      }
    }
    __builtin_amdgcn_s_waitcnt(0xC07F);

    short8 vf[4][2];
#pragma unroll
    for (int dsub = 0; dsub < 4; dsub++)
#pragma unroll
      for (int hf = 0; hf < 2; hf++)
        vf[dsub][hf] = *(const short8*)&Vl[cur][(dsub * 16 + lm) * 64 + ((4 * hf + quad) ^ (lm & 7)) * 8];

#pragma unroll
    for (int qs = 0; qs < 2; qs++) {
      short8 pf[2];
#pragma unroll
      for (int hf = 0; hf < 2; hf++)
        pf[hf] = *(const short8*)&Pw[(qs * 16 + lm) * 72 + hf * 32 + quad * 8];
#pragma unroll
      for (int dsub = 0; dsub < 4; dsub++) {
        O[qs][dsub] = __builtin_amdgcn_mfma_f32_16x16x32_bf16(pf[0], vf[dsub][0], O[qs][dsub], 0, 0, 0);
        O[qs][dsub] = __builtin_amdgcn_mfma_f32_16x16x32_bf16(pf[1], vf[dsub][1], O[qs][dsub], 0, 0, 0);
      }
      La[qs] = __builtin_amdgcn_mfma_f32_16x16x32_bf16(pf[0], ones, La[qs], 0, 0, 0);
      La[qs] = __builtin_amdgcn_mfma_f32_16x16x32_bf16(pf[1], ones, La[qs], 0, 0, 0);
    }
  }

#pragma unroll
  for (int qs = 0; qs < 2; qs++)
#pragma unroll
    for (int r = 0; r < 4; r++) {
      int n = q0 + qs * 16 + quad * 4 + r;
      float inv = 1.f / (1.f + La[qs][r]);
      int n1 = n >> 10, nn0 = n & 1023;
#pragma unroll
      for (int dsub = 0; dsub < 4; dsub++) {
        int d = dsub * 16 + lm;
        int np = d * 32 + h * 2 + n1;
        scram[((size_t)(b * NTOK + np)) * DIMC + nn0] = f2b(O[qs][dsub][r] * inv);
      }
    }
}

// ---------------- GELU (exact, erf) + row LayerNorm over HIDDEN=4096 ---------
__global__ __launch_bounds__(256) void k_ln(ushort_t* __restrict__ mid,
                                            const float* __restrict__ g,
                                            const float* __restrict__ bta) {
  const int row = blockIdx.x;
  ushort_t* p = mid + (size_t)row * HIDDEN;
  const int tid = threadIdx.x;
  float lv[16];
  float s = 0.f, s2 = 0.f;
#pragma unroll
  for (int i = 0; i < 4; i++) {
    us4 u = *(const us4*)&p[tid * 4 + i * 1024];
#pragma unroll
    for (int j = 0; j < 4; j++) {
      float xx = b2f((j == 0) ? u.x : (j == 1) ? u.y : (j == 2) ? u.z : u.w);
      xx = 0.5f * xx * (1.f + erff(xx * 0.70710678118654752f));  // exact GELU
      lv[i * 4 + j] = xx;
      s += xx;
      s2 += xx * xx;
    }
  }
#pragma unroll
  for (int off = 32; off > 0; off >>= 1) {
    s += __shfl_down(s, off);
    s2 += __shfl_down(s2, off);
  }
  __shared__ float rs[4], rs2[4];
  if ((tid & 63) == 0) { rs[tid >> 6] = s; rs2[tid >> 6] = s2; }
  __syncthreads();
  float ts = rs[0] + rs[1] + rs[2] + rs[3];
  float ts2 = rs2[0] + rs2[1] + rs2[2] + rs2[3];
  float mu = ts * (1.f / HIDDEN);
  float var = ts2 * (1.f / HIDDEN) - mu * mu;
  float rstd = rsqrtf(var + 1e-5f);
#pragma unroll
  for (int i = 0; i < 4; i++) {
    us4 o;
#pragma unroll
    for (int j = 0; j < 4; j++) {
      int f = tid * 4 + i * 1024 + j;
      float y = (lv[i * 4 + j] - mu) * rstd * g[f] + bta[f];
      ushort_t ob = f2b(y);
      if (j == 0) o.x = ob; else if (j == 1) o.y = ob; else if (j == 2) o.z = ob; else o.w = ob;
    }
    *(us4*)&p[tid * 4 + i * 1024] = o;
  }
}

extern "C" void kernel_launch(void* const* d_in, const int* in_sizes, int n_in,
                              void* d_out, int out_size, void* d_ws, size_t ws_size,
                              hipStream_t stream) {
  const float* x      = (const float*)d_in[0];
  const int*   mask   = (const int*)d_in[1];
  const float* qkv_w  = (const float*)d_in[2];
  const float* qkv_b  = (const float*)d_in[3];
  const float* proj_w = (const float*)d_in[4];
  const float* proj_b = (const float*)d_in[5];
  const float* fc1_w  = (const float*)d_in[6];
  const float* fc1_b  = (const float*)d_in[7];
  const float* ln_g   = (const float*)d_in[8];
  const float* ln_b   = (const float*)d_in[9];
  const float* fc2_w  = (const float*)d_in[10];
  const float* fc2_b  = (const float*)d_in[11];

  char* w = (char*)d_ws;
  ushort_t* qkv16  = (ushort_t*)w;           w += 3 * QSZ * 2;                    // 25.2 MB
  ushort_t* xtb    = (ushort_t*)w;           w += (size_t)MROWS * DIMC * 2;       //  8.4 MB
  ushort_t* scramb = (ushort_t*)w;           w += (size_t)MROWS * DIMC * 2;       //  8.4 MB
  ushort_t* hb     = (ushort_t*)w;           w += (size_t)MROWS * DIMC * 2;       //  8.4 MB
  ushort_t* mid    = (ushort_t*)w;           w += (size_t)MROWS * HIDDEN * 2;     // 33.6 MB
  ushort_t* wqkvb  = (ushort_t*)w;           w += (size_t)3 * DIMC * DIMC * 2;    //  6.3 MB
  ushort_t* wprojb = (ushort_t*)w;           w += (size_t)DIMC * DIMC * 2;        //  2.1 MB
  ushort_t* wfc1b  = (ushort_t*)w;           w += (size_t)HIDDEN * DIMC * 2;      //  8.4 MB
  ushort_t* wfc2b  = (ushort_t*)w;           w += (size_t)DIMC * HIDDEN * 2;      //  8.4 MB
  ushort_t* pbuf   = (ushort_t*)w;           w += (size_t)4 * MROWS * DIMC * 2;   // 33.6 MB (up to 4x bf16 partials)
  ushort_t* pbuf1  = pbuf + (size_t)MROWS * DIMC;

  k_pre<<<dim3(4096 + 12288), 256, 0, stream>>>(x, qkv_w, proj_w, fc1_w, fc2_w,
                                                xtb, wqkvb, wprojb, wfc1b, wfc2b);

  // qkv: 2-phase 128-tile, XROW (A-panel per XCD L2-resident)
  k_gemm_bf16<0, 4, DIMC, DIMC, 1><<<dim3(24 * 32), 256, 0, stream>>>(
      xtb, wqkvb, qkv_b, qkv16);
  k_attn_mfma<<<dim3(NTOK / 128, BATCH * HEADS), 256, 0, stream>>>(
      qkv16, mask, scramb);
  // proj: 2-phase, split-K=2, bf16 partials; XROW
  k_gemm_bf16<4, 4, DIMC, 512, 1><<<dim3(8 * 32, 2), 256, 0, stream>>>(
      scramb, wprojb, nullptr, pbuf);
  k_comb_proj<<<dim3(4096), 256, 0, stream>>>(pbuf, pbuf1, proj_b, hb);
  // fc1: 256x256 8-phase (256 WGs, 512 thr) — verified round 11
  k_gemm256<2, 1024, 16, 32><<<dim3(256), 512, 0, stream>>>(hb, wfc1b, fc1_b, mid);
  k_ln<<<dim3(MROWS), 256, 0, stream>>>(mid, ln_g, ln_b);
  // fc2: 256x256 8-phase, split-K=4 (64 tiles x 4 kz = 256 WGs, NT=16/slice)
  k_gemm256<4, 4096, 4, 8><<<dim3(64, 4), 512, 0, stream>>>(mid, wfc2b, nullptr, pbuf);
  k_comb_fc2<<<dim3(NTOK / 32, DIMC / 32, BATCH), dim3(32, 8), 0, stream>>>(
      pbuf, hb, fc2_b, (float*)d_out);
}